// Round 7
// baseline (466.975 us; speedup 1.0000x reference)
//
#include <hip/hip_runtime.h>
#include <stdint.h>

typedef unsigned short u16;
typedef float floatx4 __attribute__((ext_vector_type(4)));
typedef short short8 __attribute__((ext_vector_type(8)));

#define TOPK_ 256

#define AS1(p) ((const __attribute__((address_space(1))) void*)(p))
#define AS3(p) ((__attribute__((address_space(3))) void*)(p))

__device__ __forceinline__ u16 f2bf(float f) {
  unsigned u = __builtin_bit_cast(unsigned, f);
  unsigned r = (u + 0x7FFFu + ((u >> 16) & 1u)) >> 16;
  return (u16)r;
}
__device__ __forceinline__ float bf2f(u16 b) {
  unsigned u = ((unsigned)b) << 16;
  return __builtin_bit_cast(float, u);
}

// ---- DPP wave-64 sum, result uniform via readlane ----
__device__ __forceinline__ float wave_sum_f32(float x) {
#define DPP_STEP(ctrl, rmask)                                                        \
  {                                                                                  \
    float t_ = __builtin_bit_cast(                                                   \
        float, __builtin_amdgcn_update_dpp(0, __builtin_bit_cast(int, x), ctrl,      \
                                           rmask, 0xf, true));                       \
    x += t_;                                                                         \
  }
  DPP_STEP(0x111, 0xf)
  DPP_STEP(0x112, 0xf)
  DPP_STEP(0x114, 0xf)
  DPP_STEP(0x118, 0xf)
  DPP_STEP(0x142, 0xa)
  DPP_STEP(0x143, 0xc)
#undef DPP_STEP
  return __builtin_bit_cast(float,
                            __builtin_amdgcn_readlane(__builtin_bit_cast(int, x), 63));
}

// ---- two independent wave sums, DPP chains interleaved for ILP ----
__device__ __forceinline__ void wave_sum2_f32(float& x, float& y) {
#define DPP_STEP2(ctrl, rmask)                                                       \
  {                                                                                  \
    float tx_ = __builtin_bit_cast(                                                  \
        float, __builtin_amdgcn_update_dpp(0, __builtin_bit_cast(int, x), ctrl,      \
                                           rmask, 0xf, true));                       \
    float ty_ = __builtin_bit_cast(                                                  \
        float, __builtin_amdgcn_update_dpp(0, __builtin_bit_cast(int, y), ctrl,      \
                                           rmask, 0xf, true));                       \
    x += tx_;                                                                        \
    y += ty_;                                                                        \
  }
  DPP_STEP2(0x111, 0xf)
  DPP_STEP2(0x112, 0xf)
  DPP_STEP2(0x114, 0xf)
  DPP_STEP2(0x118, 0xf)
  DPP_STEP2(0x142, 0xa)
  DPP_STEP2(0x143, 0xc)
#undef DPP_STEP2
  x = __builtin_bit_cast(float, __builtin_amdgcn_readlane(__builtin_bit_cast(int, x), 63));
  y = __builtin_bit_cast(float, __builtin_amdgcn_readlane(__builtin_bit_cast(int, y), 63));
}

// ---------------- block-wide sum over 256 threads ----------------
__device__ __forceinline__ float block_sum256(float v, volatile float* scratch, int wave,
                                              int lane) {
#pragma unroll
  for (int o = 32; o > 0; o >>= 1) v += __shfl_xor(v, o);
  __syncthreads();
  if (lane == 0) scratch[wave] = v;
  __syncthreads();
  return scratch[0] + scratch[1] + scratch[2] + scratch[3];
}

// ---------------- fused prep: cast + both weight transposes + vhat ----------------
// grid: [0,8192) cast text->bf16; [8192,11264) Wqkv transpose (96x32);
//       [11264,12288) Wp2 transpose (32x32); [12288,12296) vhat.
__global__ __launch_bounds__(256) void prep_kernel(const float* __restrict__ text,
                                                   u16* __restrict__ Abf,
                                                   const float* __restrict__ Wqkv,
                                                   u16* __restrict__ Wtqkv,
                                                   const float* __restrict__ Wp2,
                                                   u16* __restrict__ Wtp2,
                                                   const float* __restrict__ vis,
                                                   float* __restrict__ vhat) {
  __shared__ u16 tile[32][33];
  __shared__ float red[4];
  int blk = blockIdx.x, t = threadIdx.x;
  if (blk < 8192) {
    int i = (blk * 256 + t) * 4;
    float4 v = *reinterpret_cast<const float4*>(text + i);
    ushort4 o;
    o.x = f2bf(v.x); o.y = f2bf(v.y); o.z = f2bf(v.z); o.w = f2bf(v.w);
    *reinterpret_cast<ushort4*>(Abf + i) = o;
  } else if (blk < 12288) {
    const float* W;
    u16* Wt;
    int cols, id;
    if (blk < 11264) { W = Wqkv; Wt = Wtqkv; cols = 3072; id = blk - 8192; }
    else             { W = Wp2;  Wt = Wtp2;  cols = 1024; id = blk - 11264; }
    int nx = cols >> 5;
    int n0 = (id % nx) * 32, k0 = (id / nx) * 32;
    int r = t >> 3, c4 = (t & 7) * 4;
    float4 v = *reinterpret_cast<const float4*>(W + (size_t)(k0 + r) * cols + n0 + c4);
    tile[r][c4 + 0] = f2bf(v.x);
    tile[r][c4 + 1] = f2bf(v.y);
    tile[r][c4 + 2] = f2bf(v.z);
    tile[r][c4 + 3] = f2bf(v.w);
    __syncthreads();
    ushort4 o;
    o.x = tile[c4 + 0][r]; o.y = tile[c4 + 1][r];
    o.z = tile[c4 + 2][r]; o.w = tile[c4 + 3][r];
    *reinterpret_cast<ushort4*>(Wt + (size_t)(n0 + r) * 1024 + k0 + c4) = o;
  } else {
    int b = blk - 12288, wave = t >> 6, lane = t & 63;
    float4 vv = *reinterpret_cast<const float4*>(vis + b * 1024 + t * 4);
    float sq = vv.x * vv.x + vv.y * vv.y + vv.z * vv.z + vv.w * vv.w;
    sq = block_sum256(sq, red, wave, lane);
    float inv = 1.f / fmaxf(sqrtf(sq), 1e-12f);
    float4 o = make_float4(vv.x * inv, vv.y * inv, vv.z * inv, vv.w * inv);
    *reinterpret_cast<float4*>(vhat + b * 1024 + t * 4) = o;
  }
}

// ---------------- bf16 GEMM, 128x128 tile, global_load_lds staging ----------------
// XCD-chunk swizzled block index (T1). Requires nwg % 8 == 0 (both call sites satisfy).
// mode 0: writes q (row-major head layout), k & v (FRAGMENT-MAJOR layouts for attn):
//   kb[bh][ktile=64][plane=2][lane=64][8]   elem = K[bh][ktile*16+(lane&15)][plane*32+(lane>>4)*8+e]
//   vb[bh][ks32=32][dtile=4][lane=64][8]    elem = V^T[bh][dtile*16+(lane&15)][ks32*32+(lane>>4)*8+e]
__global__ __launch_bounds__(256) void gemm_bt(const u16* __restrict__ A,
                                               const u16* __restrict__ Bt,
                                               const float* __restrict__ bias,
                                               int M, int Nn, int K, int mode,
                                               u16* __restrict__ qb, u16* __restrict__ kb,
                                               u16* __restrict__ vb, u16* __restrict__ yb) {
  __shared__ __align__(16) u16 SMEM[9216];
  u16* As = SMEM;
  u16* Bs = SMEM + 4096;
  // XCD swizzle: dispatch-linear id -> chunked id so each XCD works a contiguous range
  int id = blockIdx.x + blockIdx.y * gridDim.x;
  int cpx = (gridDim.x * gridDim.y) >> 3;
  int swz = (id & 7) * cpx + (id >> 3);
  int bx = swz % gridDim.x, by = swz / gridDim.x;
  int m0 = by * 128, n0 = bx * 128;
  int t = threadIdx.x, lane = t & 63, wave = t >> 6;
  int wr = wave >> 1, wc = wave & 1;
  int lrow = lane & 15, lko = (lane >> 4) * 8;
  floatx4 acc[4][4];
#pragma unroll
  for (int i = 0; i < 4; ++i)
#pragma unroll
    for (int j = 0; j < 4; ++j) acc[i][j] = (floatx4){0.f, 0.f, 0.f, 0.f};
  int srow = t >> 2, sc8 = (t & 3) * 8;
  const u16* gA0 = A + (size_t)(m0 + srow) * K + sc8;
  const u16* gA1 = A + (size_t)(m0 + srow + 64) * K + sc8;
  const u16* gB0 = Bt + (size_t)(n0 + srow) * K + sc8;
  const u16* gB1 = Bt + (size_t)(n0 + srow + 64) * K + sc8;
  for (int k0 = 0; k0 < K; k0 += 32) {
    __syncthreads();
    __builtin_amdgcn_global_load_lds(AS1(gA0 + k0), AS3(&As[t * 8]), 16, 0, 0);
    __builtin_amdgcn_global_load_lds(AS1(gA1 + k0), AS3(&As[t * 8 + 2048]), 16, 0, 0);
    __builtin_amdgcn_global_load_lds(AS1(gB0 + k0), AS3(&Bs[t * 8]), 16, 0, 0);
    __builtin_amdgcn_global_load_lds(AS1(gB1 + k0), AS3(&Bs[t * 8 + 2048]), 16, 0, 0);
    __syncthreads();
    short8 afr[4], bfr[4];
#pragma unroll
    for (int i = 0; i < 4; ++i) {
      afr[i] = *reinterpret_cast<const short8*>(&As[(wr * 64 + i * 16 + lrow) * 32 + lko]);
      bfr[i] = *reinterpret_cast<const short8*>(&Bs[(wc * 64 + i * 16 + lrow) * 32 + lko]);
    }
#pragma unroll
    for (int i = 0; i < 4; ++i)
#pragma unroll
      for (int j = 0; j < 4; ++j)
        acc[i][j] = __builtin_amdgcn_mfma_f32_16x16x32_bf16(afr[i], bfr[j], acc[i][j], 0, 0, 0);
  }
  int rb = (lane >> 4) * 4;
  if (mode == 0 && n0 >= 2048) {
    // V path: fragment-major store
#pragma unroll
    for (int i = 0; i < 4; ++i) {
#pragma unroll
      for (int j = 0; j < 4; ++j) {
        int gcol = n0 + wc * 64 + j * 16 + lrow;
        float bv = bias[gcol];
        int grow0 = m0 + wr * 64 + i * 16 + rb;
        int cc = gcol & 1023, hh = cc >> 6, dd = cc & 63;
        int bb = grow0 >> 10, nq0 = grow0 & 1023;
        size_t headq = ((size_t)bb * 16 + hh);
        int dtile = dd >> 4, drow = dd & 15;
        int ks32 = nq0 >> 5, kk = nq0 & 31, lq = kk >> 3, e = kk & 7;
        int lane2 = lq * 16 + drow;
        ushort4 o;
        o.x = f2bf(acc[i][j][0] + bv);
        o.y = f2bf(acc[i][j][1] + bv);
        o.z = f2bf(acc[i][j][2] + bv);
        o.w = f2bf(acc[i][j][3] + bv);
        *reinterpret_cast<ushort4*>(vb + headq * 65536 + (size_t)ks32 * 2048 +
                                    dtile * 512 + lane2 * 8 + e) = o;
      }
    }
  } else {
    u16* LDSC = SMEM;  // [128][72]
    for (int half = 0; half < 2; ++half) {
      __syncthreads();
      if (wc == half) {
#pragma unroll
        for (int i = 0; i < 4; ++i)
#pragma unroll
          for (int j = 0; j < 4; ++j) {
            float bv = bias[n0 + half * 64 + j * 16 + lrow];
#pragma unroll
            for (int rr = 0; rr < 4; ++rr)
              LDSC[(wr * 64 + i * 16 + rb + rr) * 72 + j * 16 + lrow] =
                  f2bf(acc[i][j][rr] + bv);
          }
      }
      __syncthreads();
      int row = t >> 4, c4 = (t & 15) * 4;
#pragma unroll
      for (int it = 0; it < 8; ++it) {
        int rw = row + it * 16;
        ushort4 val = *reinterpret_cast<const ushort4*>(&LDSC[rw * 72 + c4]);
        int grow = m0 + rw, gcol = n0 + half * 64 + c4;
        if (mode == 1) {
          *reinterpret_cast<ushort4*>(yb + (size_t)grow * 1024 + gcol) = val;
        } else {
          int sec = gcol >> 10, cc = gcol & 1023, hh = cc >> 6, dd = cc & 63;
          int bb = grow >> 10, nq = grow & 1023;
          size_t head = ((size_t)bb * 16 + hh);
          if (sec == 0) {
            *reinterpret_cast<ushort4*>(qb + (head * 1024 + nq) * 64 + dd) = val;
          } else {
            // K path: fragment-major store (4 consecutive d at fixed nq)
            int kc = nq >> 4, krow = nq & 15;
            int p = dd >> 5, quad = (dd >> 3) & 3, e = dd & 7;
            *reinterpret_cast<ushort4*>(kb + head * 65536 + (size_t)kc * 1024 +
                                        p * 512 + (quad * 16 + krow) * 8 + e) = val;
          }
        }
      }
    }
  }
}

// ---------------- fused attention, 512 threads (8 waves), 3 blocks/CU ----------------
// launch_bounds (512,6): VGPR cap ~84 so the compiler can KEEP both rows' unpacked keys
// + exp values live (at cap 64 / VGPR_Count 32 it rematerialized the unpack at every
// radix compare and exp pass — inflating VALU issue ~3x). Trades 32->24 waves/CU.
#define SSTR 1036
__global__ __launch_bounds__(512, 6) void attn_kernel(const u16* __restrict__ qb,
                                                      const u16* __restrict__ kb,
                                                      const u16* __restrict__ vb,
                                                      const int* __restrict__ mask,
                                                      u16* __restrict__ xout) {
  extern __shared__ __align__(16) char smem[];
  u16* Sb = reinterpret_cast<u16*>(smem);                               // 33152 B
  u16* qs = reinterpret_cast<u16*>(smem + 33152);                       // 2304 B
  unsigned char* mk8 = reinterpret_cast<unsigned char*>(smem + 35456);  // 1024 B
  float* invZs = reinterpret_cast<float*>(smem + 36480);                // 64 B
  float* part = reinterpret_cast<float*>(smem + 36544);                 // 4096 B

  int blk = blockIdx.x;
  int bh = blk >> 6, qt = blk & 63;
  int b = bh >> 4, h = bh & 15;
  int t = threadIdx.x, wave = t >> 6, lane = t & 63;
  const u16* qh = qb + ((size_t)bh * 1024 + qt * 16) * 64;
  const u16* kh = kb + (size_t)bh * 65536;  // fragment-major
  const u16* vh = vb + (size_t)bh * 65536;  // fragment-major

  {
    int2 mm = *reinterpret_cast<const int2*>(mask + b * 1024 + t * 2);
    u16 pk = (u16)((mm.x != 0 ? 1u : 0u) | ((mm.y != 0 ? 1u : 0u) << 8));
    *reinterpret_cast<u16*>(&mk8[t * 2]) = pk;
  }
  if (t < 256) {
    int row = t >> 4, c4 = (t & 15) * 4;
    *reinterpret_cast<ushort4*>(&qs[row * 72 + c4]) =
        *reinterpret_cast<const ushort4*>(qh + row * 64 + c4);
  }
  __syncthreads();

  int lrow = lane & 15, lko = (lane >> 4) * 8;
  int quad = lane >> 4;
  int dtile = wave & 3, kq = wave >> 2;
  const u16* vbase = vh + (size_t)(kq * 16 * 4 + dtile) * 512 + lane * 8;

  // phase 1: scores^T tiles (A = K-frag, B = Q-frag); 8 k-tiles per wave, full unroll
  // so the compiler can pipeline all 16 coalesced K loads.
  {
    short8 qf0 = *reinterpret_cast<const short8*>(&qs[lrow * 72 + lko]);
    short8 qf1 = *reinterpret_cast<const short8*>(&qs[lrow * 72 + lko + 32]);
#pragma unroll
    for (int c = 0; c < 8; ++c) {
      int kc = wave * 8 + c;
      const u16* kt = kh + (size_t)kc * 1024 + lane * 8;
      short8 kf0 = *reinterpret_cast<const short8*>(kt);
      short8 kf1 = *reinterpret_cast<const short8*>(kt + 512);
      floatx4 acc = (floatx4){0.f, 0.f, 0.f, 0.f};
      acc = __builtin_amdgcn_mfma_f32_16x16x32_bf16(kf0, qf0, acc, 0, 0, 0);
      acc = __builtin_amdgcn_mfma_f32_16x16x32_bf16(kf1, qf1, acc, 0, 0, 0);
      unsigned kk[4];
#pragma unroll
      for (int i = 0; i < 4; ++i) {
        float f = __builtin_fmaf(acc[i], 64.f, 4096.f);
        f = __builtin_amdgcn_fmed3f(f, 0.f, 8191.f);  // clamp in one op
        kk[i] = (unsigned)f;
      }
      uint2 pk;
      pk.x = __builtin_amdgcn_perm(kk[1], kk[0], 0x05040100u);  // kk0 | kk1<<16
      pk.y = __builtin_amdgcn_perm(kk[3], kk[2], 0x05040100u);
      *reinterpret_cast<uint2*>(&Sb[lrow * SSTR + kc * 16 + quad * 4]) = pk;
    }
  }
  __syncthreads();

  // V prefetch: first 4 fragments for this wave's (dtile,kq); latency hides under phase 2.
  short8 vp0 = *reinterpret_cast<const short8*>(vbase);
  short8 vp1 = *reinterpret_cast<const short8*>(vbase + 2048);
  short8 vp2 = *reinterpret_cast<const short8*>(vbase + 4096);
  short8 vp3 = *reinterpret_cast<const short8*>(vbase + 6144);
  asm volatile("" : "+v"(vp0), "+v"(vp1), "+v"(vp2), "+v"(vp3));

  // phase 2: FULLY JOINT processing of rows 2w and 2w+1 — radix, exp pass, weight pass
  // all interleaved; wave-sum DPP chains run pairwise (wave_sum2) so the two rows'
  // serial chains overlap.
  {
    const u16* SrA = Sb + (wave * 2) * SSTR;
    const u16* SrB = Sb + (wave * 2 + 1) * SSTR;
    unsigned kA[16], kB[16];
#pragma unroll
    for (int jj = 0; jj < 4; ++jj) {
      uint2 pa = *reinterpret_cast<const uint2*>(SrA + 4 * lane + 256 * jj);
      uint2 pb = *reinterpret_cast<const uint2*>(SrB + 4 * lane + 256 * jj);
      kA[4 * jj + 0] = pa.x & 0xffffu; kA[4 * jj + 1] = pa.x >> 16;
      kA[4 * jj + 2] = pa.y & 0xffffu; kA[4 * jj + 3] = pa.y >> 16;
      kB[4 * jj + 0] = pb.x & 0xffffu; kB[4 * jj + 1] = pb.x >> 16;
      kB[4 * jj + 2] = pb.y & 0xffffu; kB[4 * jj + 3] = pb.y >> 16;
    }
    unsigned TA = 0, TB = 0;
    int dA = 0, dB = 0;
    for (int bit = 12; bit >= 5; --bit) {
      unsigned cA = TA | (1u << bit), cB = TB | (1u << bit);
      int cntA = 0, cntB = 0;
#pragma unroll
      for (int i = 0; i < 16; ++i) {
        cntA += (int)__popcll(__ballot(kA[i] >= cA));
        cntB += (int)__popcll(__ballot(kB[i] >= cB));
      }
      if (!dA && cntA >= TOPK_) { TA = cA; if (cntA == TOPK_) dA = 1; }
      if (!dB && cntB >= TOPK_) { TB = cB; if (cntB == TOPK_) dB = 1; }
      if (dA && dB) break;
    }
    const float C1 = 1.44269504f / 512.f;
    const float C0 = -4096.f * (1.44269504f / 512.f);
    // exp pass, both rows (independent chains, 8-way ILP)
    float eA[16], eB[16];
    float sqA[4] = {0.f, 0.f, 0.f, 0.f}, sqB[4] = {0.f, 0.f, 0.f, 0.f};
#pragma unroll
    for (int i = 0; i < 16; ++i) {
      float exA = __builtin_amdgcn_exp2f(__builtin_fmaf((float)kA[i], C1, C0));
      float exB = __builtin_amdgcn_exp2f(__builtin_fmaf((float)kB[i], C1, C0));
      exA = (kA[i] >= TA) ? exA : 0.f;
      exB = (kB[i] >= TB) ? exB : 0.f;
      eA[i] = exA; eB[i] = exB;
      sqA[i & 3] += exA; sqB[i & 3] += exB;
    }
    float seA = (sqA[0] + sqA[1]) + (sqA[2] + sqA[3]);
    float seB = (sqB[0] + sqB[1]) + (sqB[2] + sqB[3]);
    wave_sum2_f32(seA, seB);
    float cAv = __builtin_amdgcn_rcpf(seA) * 1.44269504f;
    float cBv = __builtin_amdgcn_rcpf(seB) * 1.44269504f;
    // weight pass, both rows interleaved; mask words shared
    float ZA = 0.f, ZB = 0.f;
    u16* WrA = Sb + (wave * 2) * SSTR;
    u16* WrB = Sb + (wave * 2 + 1) * SSTR;
#pragma unroll
    for (int jj = 0; jj < 4; ++jj) {
      unsigned m = *reinterpret_cast<const unsigned*>(mk8 + 4 * lane + 256 * jj);
      float a0 = __builtin_amdgcn_exp2f(eA[4 * jj + 0] * cAv);
      float a1 = __builtin_amdgcn_exp2f(eA[4 * jj + 1] * cAv);
      float a2 = __builtin_amdgcn_exp2f(eA[4 * jj + 2] * cAv);
      float a3 = __builtin_amdgcn_exp2f(eA[4 * jj + 3] * cAv);
      float b0 = __builtin_amdgcn_exp2f(eB[4 * jj + 0] * cBv);
      float b1 = __builtin_amdgcn_exp2f(eB[4 * jj + 1] * cBv);
      float b2 = __builtin_amdgcn_exp2f(eB[4 * jj + 2] * cBv);
      float b3 = __builtin_amdgcn_exp2f(eB[4 * jj + 3] * cBv);
      a0 = (m & 0x000000ffu) ? 0.f : a0;
      a1 = (m & 0x0000ff00u) ? 0.f : a1;
      a2 = (m & 0x00ff0000u) ? 0.f : a2;
      a3 = (m & 0xff000000u) ? 0.f : a3;
      b0 = (m & 0x000000ffu) ? 0.f : b0;
      b1 = (m & 0x0000ff00u) ? 0.f : b1;
      b2 = (m & 0x00ff0000u) ? 0.f : b2;
      b3 = (m & 0xff000000u) ? 0.f : b3;
      ZA += (a0 + a1) + (a2 + a3);
      ZB += (b0 + b1) + (b2 + b3);
      uint2 pwA, pwB;
      pwA.x = __builtin_amdgcn_perm(__builtin_bit_cast(unsigned, a1),
                                    __builtin_bit_cast(unsigned, a0), 0x07060302u);
      pwA.y = __builtin_amdgcn_perm(__builtin_bit_cast(unsigned, a3),
                                    __builtin_bit_cast(unsigned, a2), 0x07060302u);
      pwB.x = __builtin_amdgcn_perm(__builtin_bit_cast(unsigned, b1),
                                    __builtin_bit_cast(unsigned, b0), 0x07060302u);
      pwB.y = __builtin_amdgcn_perm(__builtin_bit_cast(unsigned, b3),
                                    __builtin_bit_cast(unsigned, b2), 0x07060302u);
      *reinterpret_cast<uint2*>(WrA + 4 * lane + 256 * jj) = pwA;
      *reinterpret_cast<uint2*>(WrB + 4 * lane + 256 * jj) = pwB;
    }
    wave_sum2_f32(ZA, ZB);
    if (lane == 0) {
      invZs[wave * 2] = __builtin_amdgcn_rcpf(ZA);
      invZs[wave * 2 + 1] = __builtin_amdgcn_rcpf(ZB);
    }
  }
  __syncthreads();

  // phase 3: x = w @ v, K split 2 ways; wave = kq*4 + dtile.
  {
    floatx4 acc = (floatx4){0.f, 0.f, 0.f, 0.f};
    const u16* wrow = Sb + lrow * SSTR + kq * 512;
    short8 af;
    af = *reinterpret_cast<const short8*>(wrow + 0 * 32 + lko);
    acc = __builtin_amdgcn_mfma_f32_16x16x32_bf16(af, vp0, acc, 0, 0, 0);
    af = *reinterpret_cast<const short8*>(wrow + 1 * 32 + lko);
    acc = __builtin_amdgcn_mfma_f32_16x16x32_bf16(af, vp1, acc, 0, 0, 0);
    af = *reinterpret_cast<const short8*>(wrow + 2 * 32 + lko);
    acc = __builtin_amdgcn_mfma_f32_16x16x32_bf16(af, vp2, acc, 0, 0, 0);
    af = *reinterpret_cast<const short8*>(wrow + 3 * 32 + lko);
    acc = __builtin_amdgcn_mfma_f32_16x16x32_bf16(af, vp3, acc, 0, 0, 0);
#pragma unroll
    for (int ks = 4; ks < 16; ++ks) {
      short8 bf = *reinterpret_cast<const short8*>(vbase + (size_t)ks * 2048);
      short8 af2 = *reinterpret_cast<const short8*>(wrow + ks * 32 + lko);
      acc = __builtin_amdgcn_mfma_f32_16x16x32_bf16(af2, bf, acc, 0, 0, 0);
    }
    if (kq == 1)
      *reinterpret_cast<floatx4*>(part + (size_t)(dtile * 64 + lane) * 4) = acc;
    __syncthreads();
    if (kq == 0) {
      floatx4 p2 = *reinterpret_cast<const floatx4*>(part + (size_t)(dtile * 64 + lane) * 4);
      float4 iz = *reinterpret_cast<const float4*>(&invZs[quad * 4]);
      int d = dtile * 16 + lrow;
      u16* xo = xout + ((size_t)(b * 1024 + qt * 16 + quad * 4)) * 1024 + h * 64 + d;
      xo[0 * 1024] = f2bf((acc[0] + p2[0]) * iz.x);
      xo[1 * 1024] = f2bf((acc[1] + p2[1]) * iz.y);
      xo[2 * 1024] = f2bf((acc[2] + p2[2]) * iz.z);
      xo[3 * 1024] = f2bf((acc[3] + p2[3]) * iz.w);
    }
  }
}

// ---------------- residual + layernorm (bf16 y) + fused sim ----------------
__global__ __launch_bounds__(256) void resid_ln(const u16* __restrict__ y,
                                                const float* __restrict__ text,
                                                const float* __restrict__ g,
                                                const float* __restrict__ be,
                                                const float* __restrict__ vhat,
                                                const int* __restrict__ mask,
                                                const float* __restrict__ alpha,
                                                const float* __restrict__ beta,
                                                float* __restrict__ tf,
                                                float* __restrict__ sim_g) {
  __shared__ float scratch[4];
  int row = blockIdx.x, t = threadIdx.x, wave = t >> 6, lane = t & 63;
  int b = row >> 10;
  ushort4 yv = *reinterpret_cast<const ushort4*>(y + (size_t)row * 1024 + t * 4);
  float4 tv = *reinterpret_cast<const float4*>(text + (size_t)row * 1024 + t * 4);
  float v[4] = {bf2f(yv.x) + tv.x, bf2f(yv.y) + tv.y, bf2f(yv.z) + tv.z, bf2f(yv.w) + tv.w};
  float s = 0.f, sq = 0.f;
#pragma unroll
  for (int j = 0; j < 4; ++j) { s += v[j]; sq += v[j] * v[j]; }
  s = block_sum256(s, scratch, wave, lane);
  sq = block_sum256(sq, scratch, wave, lane);
  float mean = s * (1.f / 1024.f);
  float var = sq * (1.f / 1024.f) - mean * mean;
  float rs = rsqrtf(var + 1e-5f);
  float4 gv = *reinterpret_cast<const float4*>(g + t * 4);
  float4 bv = *reinterpret_cast<const float4*>(be + t * 4);
  float4 hv = *reinterpret_cast<const float4*>(vhat + b * 1024 + t * 4);
  float o[4];
  o[0] = (v[0] - mean) * rs * gv.x + bv.x;
  o[1] = (v[1] - mean) * rs * gv.y + bv.y;
  o[2] = (v[2] - mean) * rs * gv.z + bv.z;
  o[3] = (v[3] - mean) * rs * gv.w + bv.w;
  *reinterpret_cast<float4*>(tf + (size_t)row * 1024 + t * 4) = *reinterpret_cast<float4*>(o);
  float s2 = o[0] * o[0] + o[1] * o[1] + o[2] * o[2] + o[3] * o[3];
  float dd = o[0] * hv.x + o[1] * hv.y + o[2] * hv.z + o[3] * hv.w;
  s2 = block_sum256(s2, scratch, wave, lane);
  dd = block_sum256(dd, scratch, wave, lane);
  if (t == 0) {
    float den = fmaxf(sqrtf(s2), 1e-12f);
    float sv = beta[0] + alpha[0] * dd / den;
    sim_g[row] = mask[row] ? -__builtin_inff() : sv;
  }
}

// ---------------- top-256 of sim + partial pooled sum (atomic) ----------------
__global__ __launch_bounds__(256) void topk_pool(const float* __restrict__ sim_g,
                                                 const float* __restrict__ tf,
                                                 float* __restrict__ ttpre_acc) {
  __shared__ int idxl[256];
  __shared__ int scount;
  int b = blockIdx.x, p = blockIdx.y, t = threadIdx.x, lane = t & 63;
  if (t == 0) scount = 0;
  __syncthreads();
  if (t < 64) {
    unsigned uv[16];
#pragma unroll
    for (int j = 0; j < 16; ++j) {
      unsigned x = __builtin_bit_cast(unsigned, sim_g[b * 1024 + lane + 64 * j]);
      uv[j] = (x & 0x80000000u) ? ~x : (x | 0x80000000u);
    }
    unsigned T = 0;
    for (int bit = 31; bit >= 0; --bit) {
      unsigned cand = T | (1u << bit);
      int c = 0;
#pragma unroll
      for (int j = 0; j < 16; ++j) c += __popcll(__ballot(uv[j] >= cand));
      if (c >= TOPK_) {
        T = cand;
        if (c == TOPK_) break;
      }
    }
#pragma unroll
    for (int j = 0; j < 16; ++j) {
      if (uv[j] >= T) {
        int q = atomicAdd(&scount, 1);
        if (q < TOPK_) idxl[q] = lane + 64 * j;
      }
    }
  }
  __syncthreads();
  float4 pa = make_float4(0.f, 0.f, 0.f, 0.f);
  for (int i = p * 64; i < p * 64 + 64; ++i) {
    int n = idxl[i];
    float4 vr = *reinterpret_cast<const float4*>(tf + ((size_t)b * 1024 + n) * 1024 + t * 4);
    pa.x += vr.x; pa.y += vr.y; pa.z += vr.z; pa.w += vr.w;
  }
  atomicAdd(&ttpre_acc[b * 1024 + t * 4 + 0], pa.x);
  atomicAdd(&ttpre_acc[b * 1024 + t * 4 + 1], pa.y);
  atomicAdd(&ttpre_acc[b * 1024 + t * 4 + 2], pa.z);
  atomicAdd(&ttpre_acc[b * 1024 + t * 4 + 3], pa.w);
}

// ---------------- ttv = (pool/256 + txt) @ Wp1 + bp1, grid (8,16) ----------------
__global__ __launch_bounds__(256) void matvec_p1(const float* __restrict__ ttpre_acc,
                                                 const float* __restrict__ txt,
                                                 const float* __restrict__ Wp1,
                                                 const float* __restrict__ bp1,
                                                 float* __restrict__ ttv) {
  __shared__ float xs[1024];
  __shared__ float red[4][64];
  int b = blockIdx.x, q = blockIdx.y, t = threadIdx.x;
  for (int j = t; j < 1024; j += 256)
    xs[j] = ttpre_acc[b * 1024 + j] * (1.f / 256.f) + txt[b * 1024 + j];
  __syncthreads();
  int r = t >> 6, col = q * 64 + (t & 63);
  float acc = 0.f;
#pragma unroll 8
  for (int c = r * 256; c < r * 256 + 256; ++c) acc += xs[c] * Wp1[(size_t)c * 1024 + col];
  red[r][t & 63] = acc;
  __syncthreads();
  if (t < 64) {
    float o = red[0][t] + red[1][t] + red[2][t] + red[3][t] + bp1[q * 64 + t];
    ttv[b * 1024 + q * 64 + t] = o;
  }
}

// ---------------- final LN over ttv ----------------
__global__ __launch_bounds__(256) void ln_tt(const float* __restrict__ ttv,
                                             const float* __restrict__ g1,
                                             const float* __restrict__ b1,
                                             float* __restrict__ tt_out) {
  __shared__ float red[4];
  int b = blockIdx.x, t = threadIdx.x, wave = t >> 6, lane = t & 63;
  float4 v = *reinterpret_cast<const float4*>(ttv + b * 1024 + t * 4);
  float s = v.x + v.y + v.z + v.w;
  float sq = v.x * v.x + v.y * v.y + v.z * v.z + v.w * v.w;
  s = block_sum256(s, red, wave, lane);
  sq = block_sum256(sq, red, wave, lane);
  float mean = s * (1.f / 1024.f);
  float var = sq * (1.f / 1024.f) - mean * mean;
  float rs = rsqrtf(var + 1e-5f);
  float4 gv = *reinterpret_cast<const float4*>(g1 + t * 4);
  float4 bv = *reinterpret_cast<const float4*>(b1 + t * 4);
  float4 o;
  o.x = (v.x - mean) * rs * gv.x + bv.x;
  o.y = (v.y - mean) * rs * gv.y + bv.y;
  o.z = (v.z - mean) * rs * gv.z + bv.z;
  o.w = (v.w - mean) * rs * gv.w + bv.w;
  *reinterpret_cast<float4*>(tt_out + b * 1024 + t * 4) = o;
}

extern "C" void kernel_launch(void* const* d_in, const int* in_sizes, int n_in, void* d_out,
                              int out_size, void* d_ws, size_t ws_size, hipStream_t stream) {
  (void)in_sizes; (void)n_in; (void)out_size; (void)ws_size;
  const float* txt = (const float*)d_in[0];
  const float* text = (const float*)d_in[1];
  const int* mask = (const int*)d_in[2];
  const float* vis = (const float*)d_in[3];
  const float* Wqkv = (const float*)d_in[5];
  const float* bqkv = (const float*)d_in[6];
  const float* Wp2 = (const float*)d_in[7];
  const float* bp2 = (const float*)d_in[8];
  const float* g2 = (const float*)d_in[9];
  const float* b2 = (const float*)d_in[10];
  const float* alpha = (const float*)d_in[11];
  const float* beta = (const float*)d_in[12];
  const float* Wp1 = (const float*)d_in[13];
  const float* bp1 = (const float*)d_in[14];
  const float* g1 = (const float*)d_in[15];
  const float* b1 = (const float*)d_in[16];

  char* ws = (char*)d_ws;
  const size_t MB = 1u << 20;
  u16* Abf = (u16*)(ws);               // 16 MB; reused as attn-x buffer
  u16* Wtqkv = (u16*)(ws + 16 * MB);   // 6 MB
  u16* Wtp2 = (u16*)(ws + 22 * MB);    // 2 MB
  u16* qbuf = (u16*)(ws + 24 * MB);    // 16 MB
  u16* kbuf = (u16*)(ws + 40 * MB);    // 16 MB  fragment-major
  u16* vbuf = (u16*)(ws + 56 * MB);    // 16 MB  fragment-major
  u16* ybuf = (u16*)(ws + 72 * MB);    // 16 MB bf16 y
  float* vhat = (float*)(ws + 88 * MB);            // 32 KB
  float* sim_g = (float*)(ws + 88 * MB + 65536);   // 32 KB
  float* ttpre = (float*)(ws + 88 * MB + 131072);  // 32 KB
  float* ttv = (float*)(ws + 88 * MB + 196608);    // 32 KB

  float* out = (float*)d_out;
  float* tt_out = out;             // 8*1024
  float* tf_out = out + 8 * 1024;  // 8*1024*1024

  hipMemsetAsync(ttpre, 0, 8 * 1024 * sizeof(float), stream);
  prep_kernel<<<dim3(12296), dim3(256), 0, stream>>>(text, Abf, Wqkv, Wtqkv, Wp2, Wtp2, vis,
                                                     vhat);
  gemm_bt<<<dim3(24, 64), dim3(256), 0, stream>>>(Abf, Wtqkv, bqkv, 8192, 3072, 1024, 0, qbuf,
                                                  kbuf, vbuf, (u16*)nullptr);
  attn_kernel<<<dim3(8192), dim3(512), 40640, stream>>>(qbuf, kbuf, vbuf, mask, Abf);
  gemm_bt<<<dim3(8, 64), dim3(256), 0, stream>>>(Abf, Wtp2, bp2, 8192, 1024, 1024, 1,
                                                 (u16*)nullptr, (u16*)nullptr, (u16*)nullptr,
                                                 ybuf);
  resid_ln<<<dim3(8192), dim3(256), 0, stream>>>(ybuf, text, g2, b2, vhat, mask, alpha, beta,
                                                 tf_out, sim_g);
  topk_pool<<<dim3(8, 4), dim3(256), 0, stream>>>(sim_g, tf_out, ttpre);
  matvec_p1<<<dim3(8, 16), dim3(256), 0, stream>>>(ttpre, txt, Wp1, bp1, ttv);
  ln_tt<<<dim3(8), dim3(256), 0, stream>>>(ttv, g1, b1, tt_out);
}

// Round 8
// 453.895 us; speedup vs baseline: 1.0288x; 1.0288x over previous
//
#include <hip/hip_runtime.h>
#include <stdint.h>

typedef unsigned short u16;
typedef float floatx4 __attribute__((ext_vector_type(4)));
typedef short short8 __attribute__((ext_vector_type(8)));

#define TOPK_ 256

#define AS1(p) ((const __attribute__((address_space(1))) void*)(p))
#define AS3(p) ((__attribute__((address_space(3))) void*)(p))

__device__ __forceinline__ u16 f2bf(float f) {
  unsigned u = __builtin_bit_cast(unsigned, f);
  unsigned r = (u + 0x7FFFu + ((u >> 16) & 1u)) >> 16;
  return (u16)r;
}
__device__ __forceinline__ float bf2f(u16 b) {
  unsigned u = ((unsigned)b) << 16;
  return __builtin_bit_cast(float, u);
}

// ---- DPP wave-64 sum, result uniform via readlane ----
__device__ __forceinline__ float wave_sum_f32(float x) {
#define DPP_STEP(ctrl, rmask)                                                        \
  {                                                                                  \
    float t_ = __builtin_bit_cast(                                                   \
        float, __builtin_amdgcn_update_dpp(0, __builtin_bit_cast(int, x), ctrl,      \
                                           rmask, 0xf, true));                       \
    x += t_;                                                                         \
  }
  DPP_STEP(0x111, 0xf)
  DPP_STEP(0x112, 0xf)
  DPP_STEP(0x114, 0xf)
  DPP_STEP(0x118, 0xf)
  DPP_STEP(0x142, 0xa)
  DPP_STEP(0x143, 0xc)
#undef DPP_STEP
  return __builtin_bit_cast(float,
                            __builtin_amdgcn_readlane(__builtin_bit_cast(int, x), 63));
}

// ---- two independent wave sums, DPP chains interleaved for ILP ----
__device__ __forceinline__ void wave_sum2_f32(float& x, float& y) {
#define DPP_STEP2(ctrl, rmask)                                                       \
  {                                                                                  \
    float tx_ = __builtin_bit_cast(                                                  \
        float, __builtin_amdgcn_update_dpp(0, __builtin_bit_cast(int, x), ctrl,      \
                                           rmask, 0xf, true));                       \
    float ty_ = __builtin_bit_cast(                                                  \
        float, __builtin_amdgcn_update_dpp(0, __builtin_bit_cast(int, y), ctrl,      \
                                           rmask, 0xf, true));                       \
    x += tx_;                                                                        \
    y += ty_;                                                                        \
  }
  DPP_STEP2(0x111, 0xf)
  DPP_STEP2(0x112, 0xf)
  DPP_STEP2(0x114, 0xf)
  DPP_STEP2(0x118, 0xf)
  DPP_STEP2(0x142, 0xa)
  DPP_STEP2(0x143, 0xc)
#undef DPP_STEP2
  x = __builtin_bit_cast(float, __builtin_amdgcn_readlane(__builtin_bit_cast(int, x), 63));
  y = __builtin_bit_cast(float, __builtin_amdgcn_readlane(__builtin_bit_cast(int, y), 63));
}

// ---------------- block-wide sum over 256 threads ----------------
__device__ __forceinline__ float block_sum256(float v, volatile float* scratch, int wave,
                                              int lane) {
#pragma unroll
  for (int o = 32; o > 0; o >>= 1) v += __shfl_xor(v, o);
  __syncthreads();
  if (lane == 0) scratch[wave] = v;
  __syncthreads();
  return scratch[0] + scratch[1] + scratch[2] + scratch[3];
}

// ---------------- fused prep: cast + both weight transposes + vhat ----------------
// grid: [0,8192) cast text->bf16; [8192,11264) Wqkv transpose (96x32);
//       [11264,12288) Wp2 transpose (32x32); [12288,12296) vhat.
__global__ __launch_bounds__(256) void prep_kernel(const float* __restrict__ text,
                                                   u16* __restrict__ Abf,
                                                   const float* __restrict__ Wqkv,
                                                   u16* __restrict__ Wtqkv,
                                                   const float* __restrict__ Wp2,
                                                   u16* __restrict__ Wtp2,
                                                   const float* __restrict__ vis,
                                                   float* __restrict__ vhat) {
  __shared__ u16 tile[32][33];
  __shared__ float red[4];
  int blk = blockIdx.x, t = threadIdx.x;
  if (blk < 8192) {
    int i = (blk * 256 + t) * 4;
    float4 v = *reinterpret_cast<const float4*>(text + i);
    ushort4 o;
    o.x = f2bf(v.x); o.y = f2bf(v.y); o.z = f2bf(v.z); o.w = f2bf(v.w);
    *reinterpret_cast<ushort4*>(Abf + i) = o;
  } else if (blk < 12288) {
    const float* W;
    u16* Wt;
    int cols, id;
    if (blk < 11264) { W = Wqkv; Wt = Wtqkv; cols = 3072; id = blk - 8192; }
    else             { W = Wp2;  Wt = Wtp2;  cols = 1024; id = blk - 11264; }
    int nx = cols >> 5;
    int n0 = (id % nx) * 32, k0 = (id / nx) * 32;
    int r = t >> 3, c4 = (t & 7) * 4;
    float4 v = *reinterpret_cast<const float4*>(W + (size_t)(k0 + r) * cols + n0 + c4);
    tile[r][c4 + 0] = f2bf(v.x);
    tile[r][c4 + 1] = f2bf(v.y);
    tile[r][c4 + 2] = f2bf(v.z);
    tile[r][c4 + 3] = f2bf(v.w);
    __syncthreads();
    ushort4 o;
    o.x = tile[c4 + 0][r]; o.y = tile[c4 + 1][r];
    o.z = tile[c4 + 2][r]; o.w = tile[c4 + 3][r];
    *reinterpret_cast<ushort4*>(Wt + (size_t)(n0 + r) * 1024 + k0 + c4) = o;
  } else {
    int b = blk - 12288, wave = t >> 6, lane = t & 63;
    float4 vv = *reinterpret_cast<const float4*>(vis + b * 1024 + t * 4);
    float sq = vv.x * vv.x + vv.y * vv.y + vv.z * vv.z + vv.w * vv.w;
    sq = block_sum256(sq, red, wave, lane);
    float inv = 1.f / fmaxf(sqrtf(sq), 1e-12f);
    float4 o = make_float4(vv.x * inv, vv.y * inv, vv.z * inv, vv.w * inv);
    *reinterpret_cast<float4*>(vhat + b * 1024 + t * 4) = o;
  }
}

// ---------------- bf16 GEMM, 128x128 tile, global_load_lds staging ----------------
// XCD-chunk swizzled block index (T1). Requires nwg % 8 == 0 (both call sites satisfy).
// mode 0: writes q (row-major head layout), k & v (FRAGMENT-MAJOR layouts for attn):
//   kb[bh][ktile=64][plane=2][lane=64][8]   elem = K[bh][ktile*16+(lane&15)][plane*32+(lane>>4)*8+e]
//   vb[bh][ks32=32][dtile=4][lane=64][8]    elem = V^T[bh][dtile*16+(lane&15)][ks32*32+(lane>>4)*8+e]
__global__ __launch_bounds__(256) void gemm_bt(const u16* __restrict__ A,
                                               const u16* __restrict__ Bt,
                                               const float* __restrict__ bias,
                                               int M, int Nn, int K, int mode,
                                               u16* __restrict__ qb, u16* __restrict__ kb,
                                               u16* __restrict__ vb, u16* __restrict__ yb) {
  __shared__ __align__(16) u16 SMEM[9216];
  u16* As = SMEM;
  u16* Bs = SMEM + 4096;
  // XCD swizzle: dispatch-linear id -> chunked id so each XCD works a contiguous range
  int id = blockIdx.x + blockIdx.y * gridDim.x;
  int cpx = (gridDim.x * gridDim.y) >> 3;
  int swz = (id & 7) * cpx + (id >> 3);
  int bx = swz % gridDim.x, by = swz / gridDim.x;
  int m0 = by * 128, n0 = bx * 128;
  int t = threadIdx.x, lane = t & 63, wave = t >> 6;
  int wr = wave >> 1, wc = wave & 1;
  int lrow = lane & 15, lko = (lane >> 4) * 8;
  floatx4 acc[4][4];
#pragma unroll
  for (int i = 0; i < 4; ++i)
#pragma unroll
    for (int j = 0; j < 4; ++j) acc[i][j] = (floatx4){0.f, 0.f, 0.f, 0.f};
  int srow = t >> 2, sc8 = (t & 3) * 8;
  const u16* gA0 = A + (size_t)(m0 + srow) * K + sc8;
  const u16* gA1 = A + (size_t)(m0 + srow + 64) * K + sc8;
  const u16* gB0 = Bt + (size_t)(n0 + srow) * K + sc8;
  const u16* gB1 = Bt + (size_t)(n0 + srow + 64) * K + sc8;
  for (int k0 = 0; k0 < K; k0 += 32) {
    __syncthreads();
    __builtin_amdgcn_global_load_lds(AS1(gA0 + k0), AS3(&As[t * 8]), 16, 0, 0);
    __builtin_amdgcn_global_load_lds(AS1(gA1 + k0), AS3(&As[t * 8 + 2048]), 16, 0, 0);
    __builtin_amdgcn_global_load_lds(AS1(gB0 + k0), AS3(&Bs[t * 8]), 16, 0, 0);
    __builtin_amdgcn_global_load_lds(AS1(gB1 + k0), AS3(&Bs[t * 8 + 2048]), 16, 0, 0);
    __syncthreads();
    short8 afr[4], bfr[4];
#pragma unroll
    for (int i = 0; i < 4; ++i) {
      afr[i] = *reinterpret_cast<const short8*>(&As[(wr * 64 + i * 16 + lrow) * 32 + lko]);
      bfr[i] = *reinterpret_cast<const short8*>(&Bs[(wc * 64 + i * 16 + lrow) * 32 + lko]);
    }
#pragma unroll
    for (int i = 0; i < 4; ++i)
#pragma unroll
      for (int j = 0; j < 4; ++j)
        acc[i][j] = __builtin_amdgcn_mfma_f32_16x16x32_bf16(afr[i], bfr[j], acc[i][j], 0, 0, 0);
  }
  int rb = (lane >> 4) * 4;
  if (mode == 0 && n0 >= 2048) {
    // V path: fragment-major store
#pragma unroll
    for (int i = 0; i < 4; ++i) {
#pragma unroll
      for (int j = 0; j < 4; ++j) {
        int gcol = n0 + wc * 64 + j * 16 + lrow;
        float bv = bias[gcol];
        int grow0 = m0 + wr * 64 + i * 16 + rb;
        int cc = gcol & 1023, hh = cc >> 6, dd = cc & 63;
        int bb = grow0 >> 10, nq0 = grow0 & 1023;
        size_t headq = ((size_t)bb * 16 + hh);
        int dtile = dd >> 4, drow = dd & 15;
        int ks32 = nq0 >> 5, kk = nq0 & 31, lq = kk >> 3, e = kk & 7;
        int lane2 = lq * 16 + drow;
        ushort4 o;
        o.x = f2bf(acc[i][j][0] + bv);
        o.y = f2bf(acc[i][j][1] + bv);
        o.z = f2bf(acc[i][j][2] + bv);
        o.w = f2bf(acc[i][j][3] + bv);
        *reinterpret_cast<ushort4*>(vb + headq * 65536 + (size_t)ks32 * 2048 +
                                    dtile * 512 + lane2 * 8 + e) = o;
      }
    }
  } else {
    u16* LDSC = SMEM;  // [128][72]
    for (int half = 0; half < 2; ++half) {
      __syncthreads();
      if (wc == half) {
#pragma unroll
        for (int i = 0; i < 4; ++i)
#pragma unroll
          for (int j = 0; j < 4; ++j) {
            float bv = bias[n0 + half * 64 + j * 16 + lrow];
#pragma unroll
            for (int rr = 0; rr < 4; ++rr)
              LDSC[(wr * 64 + i * 16 + rb + rr) * 72 + j * 16 + lrow] =
                  f2bf(acc[i][j][rr] + bv);
          }
      }
      __syncthreads();
      int row = t >> 4, c4 = (t & 15) * 4;
#pragma unroll
      for (int it = 0; it < 8; ++it) {
        int rw = row + it * 16;
        ushort4 val = *reinterpret_cast<const ushort4*>(&LDSC[rw * 72 + c4]);
        int grow = m0 + rw, gcol = n0 + half * 64 + c4;
        if (mode == 1) {
          *reinterpret_cast<ushort4*>(yb + (size_t)grow * 1024 + gcol) = val;
        } else {
          int sec = gcol >> 10, cc = gcol & 1023, hh = cc >> 6, dd = cc & 63;
          int bb = grow >> 10, nq = grow & 1023;
          size_t head = ((size_t)bb * 16 + hh);
          if (sec == 0) {
            *reinterpret_cast<ushort4*>(qb + (head * 1024 + nq) * 64 + dd) = val;
          } else {
            // K path: fragment-major store (4 consecutive d at fixed nq)
            int kc = nq >> 4, krow = nq & 15;
            int p = dd >> 5, quad = (dd >> 3) & 3, e = dd & 7;
            *reinterpret_cast<ushort4*>(kb + head * 65536 + (size_t)kc * 1024 +
                                        p * 512 + (quad * 16 + krow) * 8 + e) = val;
          }
        }
      }
    }
  }
}

// ---------------- fused attention, 512 threads (8 waves), 4 blocks/CU ----------------
// R5-proven config: launch_bounds(512,8), joint radix, per-row pass A/B.
// (R6's (512,6)+joint-passes variant regressed: VGPR stuck at 40, occupancy 85->65.)
#define SSTR 1036
__global__ __launch_bounds__(512, 8) void attn_kernel(const u16* __restrict__ qb,
                                                      const u16* __restrict__ kb,
                                                      const u16* __restrict__ vb,
                                                      const int* __restrict__ mask,
                                                      u16* __restrict__ xout) {
  extern __shared__ __align__(16) char smem[];
  u16* Sb = reinterpret_cast<u16*>(smem);                               // 33152 B
  u16* qs = reinterpret_cast<u16*>(smem + 33152);                       // 2304 B
  unsigned char* mk8 = reinterpret_cast<unsigned char*>(smem + 35456);  // 1024 B
  float* invZs = reinterpret_cast<float*>(smem + 36480);                // 64 B
  float* part = reinterpret_cast<float*>(smem + 36544);                 // 4096 B

  int blk = blockIdx.x;
  int bh = blk >> 6, qt = blk & 63;
  int b = bh >> 4, h = bh & 15;
  int t = threadIdx.x, wave = t >> 6, lane = t & 63;
  const u16* qh = qb + ((size_t)bh * 1024 + qt * 16) * 64;
  const u16* kh = kb + (size_t)bh * 65536;  // fragment-major
  const u16* vh = vb + (size_t)bh * 65536;  // fragment-major

  {
    int2 mm = *reinterpret_cast<const int2*>(mask + b * 1024 + t * 2);
    u16 pk = (u16)((mm.x != 0 ? 1u : 0u) | ((mm.y != 0 ? 1u : 0u) << 8));
    *reinterpret_cast<u16*>(&mk8[t * 2]) = pk;
  }
  if (t < 256) {
    int row = t >> 4, c4 = (t & 15) * 4;
    *reinterpret_cast<ushort4*>(&qs[row * 72 + c4]) =
        *reinterpret_cast<const ushort4*>(qh + row * 64 + c4);
  }
  __syncthreads();

  int lrow = lane & 15, lko = (lane >> 4) * 8;
  int quad = lane >> 4;
  int dtile = wave & 3, kq = wave >> 2;
  const u16* vbase = vh + (size_t)(kq * 16 * 4 + dtile) * 512 + lane * 8;

  // phase 1: scores^T tiles (A = K-frag, B = Q-frag); 8 k-tiles per wave.
  {
    short8 qf0 = *reinterpret_cast<const short8*>(&qs[lrow * 72 + lko]);
    short8 qf1 = *reinterpret_cast<const short8*>(&qs[lrow * 72 + lko + 32]);
#pragma unroll 4
    for (int c = 0; c < 8; ++c) {
      int kc = wave * 8 + c;
      const u16* kt = kh + (size_t)kc * 1024 + lane * 8;
      short8 kf0 = *reinterpret_cast<const short8*>(kt);
      short8 kf1 = *reinterpret_cast<const short8*>(kt + 512);
      floatx4 acc = (floatx4){0.f, 0.f, 0.f, 0.f};
      acc = __builtin_amdgcn_mfma_f32_16x16x32_bf16(kf0, qf0, acc, 0, 0, 0);
      acc = __builtin_amdgcn_mfma_f32_16x16x32_bf16(kf1, qf1, acc, 0, 0, 0);
      unsigned kk[4];
#pragma unroll
      for (int i = 0; i < 4; ++i) {
        float f = __builtin_fmaf(acc[i], 64.f, 4096.f);
        f = __builtin_amdgcn_fmed3f(f, 0.f, 8191.f);  // clamp in one op
        kk[i] = (unsigned)f;
      }
      uint2 pk;
      pk.x = __builtin_amdgcn_perm(kk[1], kk[0], 0x05040100u);  // kk0 | kk1<<16
      pk.y = __builtin_amdgcn_perm(kk[3], kk[2], 0x05040100u);
      *reinterpret_cast<uint2*>(&Sb[lrow * SSTR + kc * 16 + quad * 4]) = pk;
    }
  }
  __syncthreads();

  // V prefetch: first 4 fragments for this wave's (dtile,kq); latency hides under phase 2.
  short8 vp0 = *reinterpret_cast<const short8*>(vbase);
  short8 vp1 = *reinterpret_cast<const short8*>(vbase + 2048);
  short8 vp2 = *reinterpret_cast<const short8*>(vbase + 4096);
  short8 vp3 = *reinterpret_cast<const short8*>(vbase + 6144);
  asm volatile("" : "+v"(vp0), "+v"(vp1), "+v"(vp2), "+v"(vp3));

  // phase 2: JOINT radix for rows 2w and 2w+1 — the two count chains are independent,
  // so interleaving hides each round's ballot->s_bcnt->branch serial latency.
  {
    const u16* SrA = Sb + (wave * 2) * SSTR;
    const u16* SrB = Sb + (wave * 2 + 1) * SSTR;
    unsigned kA[16], kB[16];
#pragma unroll
    for (int jj = 0; jj < 4; ++jj) {
      uint2 pa = *reinterpret_cast<const uint2*>(SrA + 4 * lane + 256 * jj);
      uint2 pb = *reinterpret_cast<const uint2*>(SrB + 4 * lane + 256 * jj);
      kA[4 * jj + 0] = pa.x & 0xffffu; kA[4 * jj + 1] = pa.x >> 16;
      kA[4 * jj + 2] = pa.y & 0xffffu; kA[4 * jj + 3] = pa.y >> 16;
      kB[4 * jj + 0] = pb.x & 0xffffu; kB[4 * jj + 1] = pb.x >> 16;
      kB[4 * jj + 2] = pb.y & 0xffffu; kB[4 * jj + 3] = pb.y >> 16;
    }
    unsigned TA = 0, TB = 0;
    int dA = 0, dB = 0;
    for (int bit = 12; bit >= 5; --bit) {
      unsigned cA = TA | (1u << bit), cB = TB | (1u << bit);
      int cntA = 0, cntB = 0;
#pragma unroll
      for (int i = 0; i < 16; ++i) {
        cntA += (int)__popcll(__ballot(kA[i] >= cA));
        cntB += (int)__popcll(__ballot(kB[i] >= cB));
      }
      if (!dA && cntA >= TOPK_) { TA = cA; if (cntA == TOPK_) dA = 1; }
      if (!dB && cntB >= TOPK_) { TB = cB; if (cntB == TOPK_) dB = 1; }
      if (dA && dB) break;
    }
    // mask words are row-invariant: load once for both rows
    unsigned mm[4];
#pragma unroll
    for (int jj = 0; jj < 4; ++jj)
      mm[jj] = *reinterpret_cast<const unsigned*>(mk8 + 4 * lane + 256 * jj);
    const float C1 = 1.44269504f / 512.f;
    const float C0 = -4096.f * (1.44269504f / 512.f);
#pragma unroll 1
    for (int rr = 0; rr < 2; ++rr) {
      int row = wave * 2 + rr;
      unsigned T = rr ? TB : TA;
      unsigned kk[16];
      if (rr == 0) {
#pragma unroll
        for (int i = 0; i < 16; ++i) kk[i] = kA[i];
      } else {
        // reload row B keys from LDS (still intact; row A's pass B only wrote row A)
        const u16* Sr = Sb + row * SSTR;
#pragma unroll
        for (int jj = 0; jj < 4; ++jj) {
          uint2 p = *reinterpret_cast<const uint2*>(Sr + 4 * lane + 256 * jj);
          kk[4 * jj + 0] = p.x & 0xffffu; kk[4 * jj + 1] = p.x >> 16;
          kk[4 * jj + 2] = p.y & 0xffffu; kk[4 * jj + 3] = p.y >> 16;
        }
      }
      // pass A: e = exp(s) for selected; se = sum (4-way ILP accumulators).
      float e[16];
      float seq[4] = {0.f, 0.f, 0.f, 0.f};
#pragma unroll
      for (int i = 0; i < 16; ++i) {
        float ex = __builtin_amdgcn_exp2f(__builtin_fmaf((float)kk[i], C1, C0));
        ex = (kk[i] >= T) ? ex : 0.f;
        e[i] = ex;
        seq[i & 3] += ex;
      }
      float se = wave_sum_f32((seq[0] + seq[1]) + (seq[2] + seq[3]));
      float cB2 = __builtin_amdgcn_rcpf(se) * 1.44269504f;
      // pass B: w = masked?0:exp2(e*cB); packed b64 writes; Z accumulated
      float Z = 0.f;
      u16* Wr = Sb + row * SSTR;
#pragma unroll
      for (int jj = 0; jj < 4; ++jj) {
        unsigned m = mm[jj];
        float w0 = __builtin_amdgcn_exp2f(e[4 * jj + 0] * cB2);
        float w1 = __builtin_amdgcn_exp2f(e[4 * jj + 1] * cB2);
        float w2 = __builtin_amdgcn_exp2f(e[4 * jj + 2] * cB2);
        float w3 = __builtin_amdgcn_exp2f(e[4 * jj + 3] * cB2);
        w0 = (m & 0x000000ffu) ? 0.f : w0;
        w1 = (m & 0x0000ff00u) ? 0.f : w1;
        w2 = (m & 0x00ff0000u) ? 0.f : w2;
        w3 = (m & 0xff000000u) ? 0.f : w3;
        Z += (w0 + w1) + (w2 + w3);
        uint2 pw;
        pw.x = __builtin_amdgcn_perm(__builtin_bit_cast(unsigned, w1),
                                     __builtin_bit_cast(unsigned, w0), 0x07060302u);
        pw.y = __builtin_amdgcn_perm(__builtin_bit_cast(unsigned, w3),
                                     __builtin_bit_cast(unsigned, w2), 0x07060302u);
        *reinterpret_cast<uint2*>(Wr + 4 * lane + 256 * jj) = pw;
      }
      Z = wave_sum_f32(Z);
      if (lane == 0) invZs[row] = __builtin_amdgcn_rcpf(Z);
    }
  }
  __syncthreads();

  // phase 3: x = w @ v, K split 2 ways; wave = kq*4 + dtile.
  {
    floatx4 acc = (floatx4){0.f, 0.f, 0.f, 0.f};
    const u16* wrow = Sb + lrow * SSTR + kq * 512;
    short8 af;
    af = *reinterpret_cast<const short8*>(wrow + 0 * 32 + lko);
    acc = __builtin_amdgcn_mfma_f32_16x16x32_bf16(af, vp0, acc, 0, 0, 0);
    af = *reinterpret_cast<const short8*>(wrow + 1 * 32 + lko);
    acc = __builtin_amdgcn_mfma_f32_16x16x32_bf16(af, vp1, acc, 0, 0, 0);
    af = *reinterpret_cast<const short8*>(wrow + 2 * 32 + lko);
    acc = __builtin_amdgcn_mfma_f32_16x16x32_bf16(af, vp2, acc, 0, 0, 0);
    af = *reinterpret_cast<const short8*>(wrow + 3 * 32 + lko);
    acc = __builtin_amdgcn_mfma_f32_16x16x32_bf16(af, vp3, acc, 0, 0, 0);
#pragma unroll
    for (int ks = 4; ks < 16; ++ks) {
      short8 bf = *reinterpret_cast<const short8*>(vbase + (size_t)ks * 2048);
      short8 af2 = *reinterpret_cast<const short8*>(wrow + ks * 32 + lko);
      acc = __builtin_amdgcn_mfma_f32_16x16x32_bf16(af2, bf, acc, 0, 0, 0);
    }
    if (kq == 1)
      *reinterpret_cast<floatx4*>(part + (size_t)(dtile * 64 + lane) * 4) = acc;
    __syncthreads();
    if (kq == 0) {
      floatx4 p2 = *reinterpret_cast<const floatx4*>(part + (size_t)(dtile * 64 + lane) * 4);
      float4 iz = *reinterpret_cast<const float4*>(&invZs[quad * 4]);
      int d = dtile * 16 + lrow;
      u16* xo = xout + ((size_t)(b * 1024 + qt * 16 + quad * 4)) * 1024 + h * 64 + d;
      xo[0 * 1024] = f2bf((acc[0] + p2[0]) * iz.x);
      xo[1 * 1024] = f2bf((acc[1] + p2[1]) * iz.y);
      xo[2 * 1024] = f2bf((acc[2] + p2[2]) * iz.z);
      xo[3 * 1024] = f2bf((acc[3] + p2[3]) * iz.w);
    }
  }
}

// ---------------- residual + layernorm + fused sim: ONE WAVE PER ROW ----------------
// 512 threads = 8 waves = 8 rows/block; zero __syncthreads (DPP-only reductions).
// 16 elems/lane at cols i*256 + lane*4 + e (unit-stride float4/ushort4 loads).
__global__ void resid_ln(const u16* __restrict__ y,
                         const float* __restrict__ text,
                         const float* __restrict__ g,
                         const float* __restrict__ be,
                         const float* __restrict__ vhat,
                         const int* __restrict__ mask,
                         const float* __restrict__ alpha,
                         const float* __restrict__ beta,
                         float* __restrict__ tf,
                         float* __restrict__ sim_g) {
  int wave = threadIdx.x >> 6, lane = threadIdx.x & 63;
  int row = blockIdx.x * 8 + wave;
  int b = row >> 10;
  size_t rbase = (size_t)row * 1024;
  int c0 = lane * 4;
  float v[16];
  float s = 0.f, sq = 0.f;
#pragma unroll
  for (int i = 0; i < 4; ++i) {
    float4 tv = *reinterpret_cast<const float4*>(text + rbase + i * 256 + c0);
    ushort4 yv = *reinterpret_cast<const ushort4*>(y + rbase + i * 256 + c0);
    float a0 = bf2f(yv.x) + tv.x;
    float a1 = bf2f(yv.y) + tv.y;
    float a2 = bf2f(yv.z) + tv.z;
    float a3 = bf2f(yv.w) + tv.w;
    v[i * 4 + 0] = a0; v[i * 4 + 1] = a1; v[i * 4 + 2] = a2; v[i * 4 + 3] = a3;
    s += (a0 + a1) + (a2 + a3);
    sq += (a0 * a0 + a1 * a1) + (a2 * a2 + a3 * a3);
  }
  wave_sum2_f32(s, sq);
  float mean = s * (1.f / 1024.f);
  float var = sq * (1.f / 1024.f) - mean * mean;
  float rs = rsqrtf(var + 1e-5f);
  float s2 = 0.f, dd = 0.f;
#pragma unroll
  for (int i = 0; i < 4; ++i) {
    float4 gv = *reinterpret_cast<const float4*>(g + i * 256 + c0);
    float4 bv = *reinterpret_cast<const float4*>(be + i * 256 + c0);
    float4 hv = *reinterpret_cast<const float4*>(vhat + b * 1024 + i * 256 + c0);
    float o0 = (v[i * 4 + 0] - mean) * rs * gv.x + bv.x;
    float o1 = (v[i * 4 + 1] - mean) * rs * gv.y + bv.y;
    float o2 = (v[i * 4 + 2] - mean) * rs * gv.z + bv.z;
    float o3 = (v[i * 4 + 3] - mean) * rs * gv.w + bv.w;
    float4 ov = make_float4(o0, o1, o2, o3);
    *reinterpret_cast<float4*>(tf + rbase + i * 256 + c0) = ov;
    s2 += (o0 * o0 + o1 * o1) + (o2 * o2 + o3 * o3);
    dd += (o0 * hv.x + o1 * hv.y) + (o2 * hv.z + o3 * hv.w);
  }
  wave_sum2_f32(s2, dd);
  if (lane == 0) {
    float den = fmaxf(sqrtf(s2), 1e-12f);
    float sv = beta[0] + alpha[0] * dd / den;
    sim_g[row] = mask[row] ? -__builtin_inff() : sv;
  }
}

// ---------------- top-256 of sim + partial pooled sum (atomic) ----------------
__global__ __launch_bounds__(256) void topk_pool(const float* __restrict__ sim_g,
                                                 const float* __restrict__ tf,
                                                 float* __restrict__ ttpre_acc) {
  __shared__ int idxl[256];
  __shared__ int scount;
  int b = blockIdx.x, p = blockIdx.y, t = threadIdx.x, lane = t & 63;
  if (t == 0) scount = 0;
  __syncthreads();
  if (t < 64) {
    unsigned uv[16];
#pragma unroll
    for (int j = 0; j < 16; ++j) {
      unsigned x = __builtin_bit_cast(unsigned, sim_g[b * 1024 + lane + 64 * j]);
      uv[j] = (x & 0x80000000u) ? ~x : (x | 0x80000000u);
    }
    unsigned T = 0;
    for (int bit = 31; bit >= 0; --bit) {
      unsigned cand = T | (1u << bit);
      int c = 0;
#pragma unroll
      for (int j = 0; j < 16; ++j) c += __popcll(__ballot(uv[j] >= cand));
      if (c >= TOPK_) {
        T = cand;
        if (c == TOPK_) break;
      }
    }
#pragma unroll
    for (int j = 0; j < 16; ++j) {
      if (uv[j] >= T) {
        int q = atomicAdd(&scount, 1);
        if (q < TOPK_) idxl[q] = lane + 64 * j;
      }
    }
  }
  __syncthreads();
  float4 pa = make_float4(0.f, 0.f, 0.f, 0.f);
  for (int i = p * 64; i < p * 64 + 64; ++i) {
    int n = idxl[i];
    float4 vr = *reinterpret_cast<const float4*>(tf + ((size_t)b * 1024 + n) * 1024 + t * 4);
    pa.x += vr.x; pa.y += vr.y; pa.z += vr.z; pa.w += vr.w;
  }
  atomicAdd(&ttpre_acc[b * 1024 + t * 4 + 0], pa.x);
  atomicAdd(&ttpre_acc[b * 1024 + t * 4 + 1], pa.y);
  atomicAdd(&ttpre_acc[b * 1024 + t * 4 + 2], pa.z);
  atomicAdd(&ttpre_acc[b * 1024 + t * 4 + 3], pa.w);
}

// ---------------- ttv = (pool/256 + txt) @ Wp1 + bp1, grid (8,16) ----------------
__global__ __launch_bounds__(256) void matvec_p1(const float* __restrict__ ttpre_acc,
                                                 const float* __restrict__ txt,
                                                 const float* __restrict__ Wp1,
                                                 const float* __restrict__ bp1,
                                                 float* __restrict__ ttv) {
  __shared__ float xs[1024];
  __shared__ float red[4][64];
  int b = blockIdx.x, q = blockIdx.y, t = threadIdx.x;
  for (int j = t; j < 1024; j += 256)
    xs[j] = ttpre_acc[b * 1024 + j] * (1.f / 256.f) + txt[b * 1024 + j];
  __syncthreads();
  int r = t >> 6, col = q * 64 + (t & 63);
  float acc = 0.f;
#pragma unroll 8
  for (int c = r * 256; c < r * 256 + 256; ++c) acc += xs[c] * Wp1[(size_t)c * 1024 + col];
  red[r][t & 63] = acc;
  __syncthreads();
  if (t < 64) {
    float o = red[0][t] + red[1][t] + red[2][t] + red[3][t] + bp1[q * 64 + t];
    ttv[b * 1024 + q * 64 + t] = o;
  }
}

// ---------------- final LN over ttv ----------------
__global__ __launch_bounds__(256) void ln_tt(const float* __restrict__ ttv,
                                             const float* __restrict__ g1,
                                             const float* __restrict__ b1,
                                             float* __restrict__ tt_out) {
  __shared__ float red[4];
  int b = blockIdx.x, t = threadIdx.x, wave = t >> 6, lane = t & 63;
  float4 v = *reinterpret_cast<const float4*>(ttv + b * 1024 + t * 4);
  float s = v.x + v.y + v.z + v.w;
  float sq = v.x * v.x + v.y * v.y + v.z * v.z + v.w * v.w;
  s = block_sum256(s, red, wave, lane);
  sq = block_sum256(sq, red, wave, lane);
  float mean = s * (1.f / 1024.f);
  float var = sq * (1.f / 1024.f) - mean * mean;
  float rs = rsqrtf(var + 1e-5f);
  float4 gv = *reinterpret_cast<const float4*>(g1 + t * 4);
  float4 bv = *reinterpret_cast<const float4*>(b1 + t * 4);
  float4 o;
  o.x = (v.x - mean) * rs * gv.x + bv.x;
  o.y = (v.y - mean) * rs * gv.y + bv.y;
  o.z = (v.z - mean) * rs * gv.z + bv.z;
  o.w = (v.w - mean) * rs * gv.w + bv.w;
  *reinterpret_cast<float4*>(tt_out + b * 1024 + t * 4) = o;
}

extern "C" void kernel_launch(void* const* d_in, const int* in_sizes, int n_in, void* d_out,
                              int out_size, void* d_ws, size_t ws_size, hipStream_t stream) {
  (void)in_sizes; (void)n_in; (void)out_size; (void)ws_size;
  const float* txt = (const float*)d_in[0];
  const float* text = (const float*)d_in[1];
  const int* mask = (const int*)d_in[2];
  const float* vis = (const float*)d_in[3];
  const float* Wqkv = (const float*)d_in[5];
  const float* bqkv = (const float*)d_in[6];
  const float* Wp2 = (const float*)d_in[7];
  const float* bp2 = (const float*)d_in[8];
  const float* g2 = (const float*)d_in[9];
  const float* b2 = (const float*)d_in[10];
  const float* alpha = (const float*)d_in[11];
  const float* beta = (const float*)d_in[12];
  const float* Wp1 = (const float*)d_in[13];
  const float* bp1 = (const float*)d_in[14];
  const float* g1 = (const float*)d_in[15];
  const float* b1 = (const float*)d_in[16];

  char* ws = (char*)d_ws;
  const size_t MB = 1u << 20;
  u16* Abf = (u16*)(ws);               // 16 MB; reused as attn-x buffer
  u16* Wtqkv = (u16*)(ws + 16 * MB);   // 6 MB
  u16* Wtp2 = (u16*)(ws + 22 * MB);    // 2 MB
  u16* qbuf = (u16*)(ws + 24 * MB);    // 16 MB
  u16* kbuf = (u16*)(ws + 40 * MB);    // 16 MB  fragment-major
  u16* vbuf = (u16*)(ws + 56 * MB);    // 16 MB  fragment-major
  u16* ybuf = (u16*)(ws + 72 * MB);    // 16 MB bf16 y
  float* vhat = (float*)(ws + 88 * MB);            // 32 KB
  float* sim_g = (float*)(ws + 88 * MB + 65536);   // 32 KB
  float* ttpre = (float*)(ws + 88 * MB + 131072);  // 32 KB
  float* ttv = (float*)(ws + 88 * MB + 196608);    // 32 KB

  float* out = (float*)d_out;
  float* tt_out = out;             // 8*1024
  float* tf_out = out + 8 * 1024;  // 8*1024*1024

  hipMemsetAsync(ttpre, 0, 8 * 1024 * sizeof(float), stream);
  prep_kernel<<<dim3(12296), dim3(256), 0, stream>>>(text, Abf, Wqkv, Wtqkv, Wp2, Wtp2, vis,
                                                     vhat);
  gemm_bt<<<dim3(24, 64), dim3(256), 0, stream>>>(Abf, Wtqkv, bqkv, 8192, 3072, 1024, 0, qbuf,
                                                  kbuf, vbuf, (u16*)nullptr);
  attn_kernel<<<dim3(8192), dim3(512), 40640, stream>>>(qbuf, kbuf, vbuf, mask, Abf);
  gemm_bt<<<dim3(8, 64), dim3(256), 0, stream>>>(Abf, Wtp2, bp2, 8192, 1024, 1024, 1,
                                                 (u16*)nullptr, (u16*)nullptr, (u16*)nullptr,
                                                 ybuf);
  resid_ln<<<dim3(1024), dim3(512), 0, stream>>>(ybuf, text, g2, b2, vhat, mask, alpha, beta,
                                                 tf_out, sim_g);
  topk_pool<<<dim3(8, 4), dim3(256), 0, stream>>>(sim_g, tf_out, ttpre);
  matvec_p1<<<dim3(8, 16), dim3(256), 0, stream>>>(ttpre, txt, Wp1, bp1, ttv);
  ln_tt<<<dim3(8), dim3(256), 0, stream>>>(ttv, g1, b1, tt_out);
}

// Round 9
// 437.458 us; speedup vs baseline: 1.0675x; 1.0376x over previous
//
#include <hip/hip_runtime.h>
#include <stdint.h>

typedef unsigned short u16;
typedef float floatx4 __attribute__((ext_vector_type(4)));
typedef short short8 __attribute__((ext_vector_type(8)));

#define TOPK_ 256

#define AS1(p) ((const __attribute__((address_space(1))) void*)(p))
#define AS3(p) ((__attribute__((address_space(3))) void*)(p))

__device__ __forceinline__ u16 f2bf(float f) {
  unsigned u = __builtin_bit_cast(unsigned, f);
  unsigned r = (u + 0x7FFFu + ((u >> 16) & 1u)) >> 16;
  return (u16)r;
}
__device__ __forceinline__ float bf2f(u16 b) {
  unsigned u = ((unsigned)b) << 16;
  return __builtin_bit_cast(float, u);
}

// ---- DPP wave-64 sum, result uniform via readlane ----
__device__ __forceinline__ float wave_sum_f32(float x) {
#define DPP_STEP(ctrl, rmask)                                                        \
  {                                                                                  \
    float t_ = __builtin_bit_cast(                                                   \
        float, __builtin_amdgcn_update_dpp(0, __builtin_bit_cast(int, x), ctrl,      \
                                           rmask, 0xf, true));                       \
    x += t_;                                                                         \
  }
  DPP_STEP(0x111, 0xf)
  DPP_STEP(0x112, 0xf)
  DPP_STEP(0x114, 0xf)
  DPP_STEP(0x118, 0xf)
  DPP_STEP(0x142, 0xa)
  DPP_STEP(0x143, 0xc)
#undef DPP_STEP
  return __builtin_bit_cast(float,
                            __builtin_amdgcn_readlane(__builtin_bit_cast(int, x), 63));
}

// ---- two independent wave sums, DPP chains interleaved for ILP ----
__device__ __forceinline__ void wave_sum2_f32(float& x, float& y) {
#define DPP_STEP2(ctrl, rmask)                                                       \
  {                                                                                  \
    float tx_ = __builtin_bit_cast(                                                  \
        float, __builtin_amdgcn_update_dpp(0, __builtin_bit_cast(int, x), ctrl,      \
                                           rmask, 0xf, true));                       \
    float ty_ = __builtin_bit_cast(                                                  \
        float, __builtin_amdgcn_update_dpp(0, __builtin_bit_cast(int, y), ctrl,      \
                                           rmask, 0xf, true));                       \
    x += tx_;                                                                        \
    y += ty_;                                                                        \
  }
  DPP_STEP2(0x111, 0xf)
  DPP_STEP2(0x112, 0xf)
  DPP_STEP2(0x114, 0xf)
  DPP_STEP2(0x118, 0xf)
  DPP_STEP2(0x142, 0xa)
  DPP_STEP2(0x143, 0xc)
#undef DPP_STEP2
  x = __builtin_bit_cast(float, __builtin_amdgcn_readlane(__builtin_bit_cast(int, x), 63));
  y = __builtin_bit_cast(float, __builtin_amdgcn_readlane(__builtin_bit_cast(int, y), 63));
}

// ---------------- block-wide sum over 256 threads ----------------
__device__ __forceinline__ float block_sum256(float v, volatile float* scratch, int wave,
                                              int lane) {
#pragma unroll
  for (int o = 32; o > 0; o >>= 1) v += __shfl_xor(v, o);
  __syncthreads();
  if (lane == 0) scratch[wave] = v;
  __syncthreads();
  return scratch[0] + scratch[1] + scratch[2] + scratch[3];
}

// ---------------- fused prep: cast + both weight transposes + vhat ----------------
__global__ __launch_bounds__(256) void prep_kernel(const float* __restrict__ text,
                                                   u16* __restrict__ Abf,
                                                   const float* __restrict__ Wqkv,
                                                   u16* __restrict__ Wtqkv,
                                                   const float* __restrict__ Wp2,
                                                   u16* __restrict__ Wtp2,
                                                   const float* __restrict__ vis,
                                                   float* __restrict__ vhat) {
  __shared__ u16 tile[32][33];
  __shared__ float red[4];
  int blk = blockIdx.x, t = threadIdx.x;
  if (blk < 8192) {
    int i = (blk * 256 + t) * 4;
    float4 v = *reinterpret_cast<const float4*>(text + i);
    ushort4 o;
    o.x = f2bf(v.x); o.y = f2bf(v.y); o.z = f2bf(v.z); o.w = f2bf(v.w);
    *reinterpret_cast<ushort4*>(Abf + i) = o;
  } else if (blk < 12288) {
    const float* W;
    u16* Wt;
    int cols, id;
    if (blk < 11264) { W = Wqkv; Wt = Wtqkv; cols = 3072; id = blk - 8192; }
    else             { W = Wp2;  Wt = Wtp2;  cols = 1024; id = blk - 11264; }
    int nx = cols >> 5;
    int n0 = (id % nx) * 32, k0 = (id / nx) * 32;
    int r = t >> 3, c4 = (t & 7) * 4;
    float4 v = *reinterpret_cast<const float4*>(W + (size_t)(k0 + r) * cols + n0 + c4);
    tile[r][c4 + 0] = f2bf(v.x);
    tile[r][c4 + 1] = f2bf(v.y);
    tile[r][c4 + 2] = f2bf(v.z);
    tile[r][c4 + 3] = f2bf(v.w);
    __syncthreads();
    ushort4 o;
    o.x = tile[c4 + 0][r]; o.y = tile[c4 + 1][r];
    o.z = tile[c4 + 2][r]; o.w = tile[c4 + 3][r];
    *reinterpret_cast<ushort4*>(Wt + (size_t)(n0 + r) * 1024 + k0 + c4) = o;
  } else {
    int b = blk - 12288, wave = t >> 6, lane = t & 63;
    float4 vv = *reinterpret_cast<const float4*>(vis + b * 1024 + t * 4);
    float sq = vv.x * vv.x + vv.y * vv.y + vv.z * vv.z + vv.w * vv.w;
    sq = block_sum256(sq, red, wave, lane);
    float inv = 1.f / fmaxf(sqrtf(sq), 1e-12f);
    float4 o = make_float4(vv.x * inv, vv.y * inv, vv.z * inv, vv.w * inv);
    *reinterpret_cast<float4*>(vhat + b * 1024 + t * 4) = o;
  }
}

// ---------------- bf16 GEMM, 128x128 tile, TRIPLE-buffered global_load_lds ----------------
// K-loop: stage kt+2 while computing kt; raw s_barrier + counted s_waitcnt vmcnt(8)
// (never 0 in steady state). In-flight loads always target bufs (kt+1)%3,(kt+2)%3
// != current kt%3 -> no overwrite race; per-wave vmcnt(8)+barrier proves all waves'
// kt loads landed; buffer overwrite issues only after the barrier following its
// last read (+ lgkmcnt(0)). Replaces the __syncthreads vmcnt(0)-drain that exposed
// full staging latency every K-step (the documented m97-structure stall).
__global__ __launch_bounds__(256) void gemm_bt(const u16* __restrict__ A,
                                               const u16* __restrict__ Bt,
                                               const float* __restrict__ bias,
                                               int M, int Nn, int K, int mode,
                                               u16* __restrict__ qb, u16* __restrict__ kb,
                                               u16* __restrict__ vb, u16* __restrict__ yb) {
  __shared__ __align__(16) u16 SMEM[24576];  // 3 bufs x (A 4096 + B 4096) u16 = 48KB
  // XCD swizzle: dispatch-linear id -> chunked id so each XCD works a contiguous range
  int id = blockIdx.x + blockIdx.y * gridDim.x;
  int cpx = (gridDim.x * gridDim.y) >> 3;
  int swz = (id & 7) * cpx + (id >> 3);
  int bx = swz % gridDim.x, by = swz / gridDim.x;
  int m0 = by * 128, n0 = bx * 128;
  int t = threadIdx.x, lane = t & 63, wave = t >> 6;
  int wr = wave >> 1, wc = wave & 1;
  int lrow = lane & 15, lko = (lane >> 4) * 8;
  floatx4 acc[4][4];
#pragma unroll
  for (int i = 0; i < 4; ++i)
#pragma unroll
    for (int j = 0; j < 4; ++j) acc[i][j] = (floatx4){0.f, 0.f, 0.f, 0.f};
  int srow = t >> 2, sc8 = (t & 3) * 8;
  const u16* gA0 = A + (size_t)(m0 + srow) * K + sc8;
  const u16* gA1 = A + (size_t)(m0 + srow + 64) * K + sc8;
  const u16* gB0 = Bt + (size_t)(n0 + srow) * K + sc8;
  const u16* gB1 = Bt + (size_t)(n0 + srow + 64) * K + sc8;

#define STAGE_KT(ktv, bufv)                                                              \
  {                                                                                      \
    int koff_ = (ktv) * 32;                                                              \
    u16* dst_ = SMEM + (bufv) * 8192 + t * 8;                                            \
    __builtin_amdgcn_global_load_lds(AS1(gA0 + koff_), AS3(dst_), 16, 0, 0);             \
    __builtin_amdgcn_global_load_lds(AS1(gA1 + koff_), AS3(dst_ + 2048), 16, 0, 0);      \
    __builtin_amdgcn_global_load_lds(AS1(gB0 + koff_), AS3(dst_ + 4096), 16, 0, 0);      \
    __builtin_amdgcn_global_load_lds(AS1(gB1 + koff_), AS3(dst_ + 6144), 16, 0, 0);      \
  }

  // prologue: stage kt=0 (buf0) and kt=1 (buf1)
  STAGE_KT(0, 0)
  STAGE_KT(1, 1)
  int cb = 0;  // buf of current kt
  const int NKT = 32;  // K/32 (K==1024 at both call sites)
#pragma unroll 1
  for (int kt = 0; kt < NKT; ++kt) {
    int kn = kt + 2;
    if (kn < NKT) {
      int bn = cb + 2; if (bn >= 3) bn -= 3;
      STAGE_KT(kn, bn)
    }
    // wait: kt's 4 loads landed (per wave); kt+1/kt+2's 8 may stay in flight
    if (kt < NKT - 2)       asm volatile("s_waitcnt vmcnt(8)" ::: "memory");
    else if (kt == NKT - 2) asm volatile("s_waitcnt vmcnt(4)" ::: "memory");
    else                    asm volatile("s_waitcnt vmcnt(0)" ::: "memory");
    __builtin_amdgcn_s_barrier();
    const u16* Asb = SMEM + cb * 8192;
    const u16* Bsb = Asb + 4096;
    short8 afr[4], bfr[4];
#pragma unroll
    for (int i = 0; i < 4; ++i) {
      afr[i] = *reinterpret_cast<const short8*>(&Asb[(wr * 64 + i * 16 + lrow) * 32 + lko]);
      bfr[i] = *reinterpret_cast<const short8*>(&Bsb[(wc * 64 + i * 16 + lrow) * 32 + lko]);
    }
#pragma unroll
    for (int i = 0; i < 4; ++i)
#pragma unroll
      for (int j = 0; j < 4; ++j)
        acc[i][j] = __builtin_amdgcn_mfma_f32_16x16x32_bf16(afr[i], bfr[j], acc[i][j], 0, 0, 0);
    // all my ds_reads complete before anyone overwrites this buf next iter
    asm volatile("s_waitcnt lgkmcnt(0)" ::: "memory");
    __builtin_amdgcn_s_barrier();
    cb = (cb == 2) ? 0 : cb + 1;
  }
#undef STAGE_KT

  int rb = (lane >> 4) * 4;
  if (mode == 0 && n0 >= 2048) {
    // V path: fragment-major store
#pragma unroll
    for (int i = 0; i < 4; ++i) {
#pragma unroll
      for (int j = 0; j < 4; ++j) {
        int gcol = n0 + wc * 64 + j * 16 + lrow;
        float bv = bias[gcol];
        int grow0 = m0 + wr * 64 + i * 16 + rb;
        int cc = gcol & 1023, hh = cc >> 6, dd = cc & 63;
        int bb = grow0 >> 10, nq0 = grow0 & 1023;
        size_t headq = ((size_t)bb * 16 + hh);
        int dtile = dd >> 4, drow = dd & 15;
        int ks32 = nq0 >> 5, kk = nq0 & 31, lq = kk >> 3, e = kk & 7;
        int lane2 = lq * 16 + drow;
        ushort4 o;
        o.x = f2bf(acc[i][j][0] + bv);
        o.y = f2bf(acc[i][j][1] + bv);
        o.z = f2bf(acc[i][j][2] + bv);
        o.w = f2bf(acc[i][j][3] + bv);
        *reinterpret_cast<ushort4*>(vb + headq * 65536 + (size_t)ks32 * 2048 +
                                    dtile * 512 + lane2 * 8 + e) = o;
      }
    }
  } else {
    u16* LDSC = SMEM;  // [128][72]
    for (int half = 0; half < 2; ++half) {
      __syncthreads();
      if (wc == half) {
#pragma unroll
        for (int i = 0; i < 4; ++i)
#pragma unroll
          for (int j = 0; j < 4; ++j) {
            float bv = bias[n0 + half * 64 + j * 16 + lrow];
#pragma unroll
            for (int rr = 0; rr < 4; ++rr)
              LDSC[(wr * 64 + i * 16 + rb + rr) * 72 + j * 16 + lrow] =
                  f2bf(acc[i][j][rr] + bv);
          }
      }
      __syncthreads();
      int row = t >> 4, c4 = (t & 15) * 4;
#pragma unroll
      for (int it = 0; it < 8; ++it) {
        int rw = row + it * 16;
        ushort4 val = *reinterpret_cast<const ushort4*>(&LDSC[rw * 72 + c4]);
        int grow = m0 + rw, gcol = n0 + half * 64 + c4;
        if (mode == 1) {
          *reinterpret_cast<ushort4*>(yb + (size_t)grow * 1024 + gcol) = val;
        } else {
          int sec = gcol >> 10, cc = gcol & 1023, hh = cc >> 6, dd = cc & 63;
          int bb = grow >> 10, nq = grow & 1023;
          size_t head = ((size_t)bb * 16 + hh);
          if (sec == 0) {
            *reinterpret_cast<ushort4*>(qb + (head * 1024 + nq) * 64 + dd) = val;
          } else {
            // K path: fragment-major store (4 consecutive d at fixed nq)
            int kc = nq >> 4, krow = nq & 15;
            int p = dd >> 5, quad = (dd >> 3) & 3, e = dd & 7;
            *reinterpret_cast<ushort4*>(kb + head * 65536 + (size_t)kc * 1024 +
                                        p * 512 + (quad * 16 + krow) * 8 + e) = val;
          }
        }
      }
    }
  }
}

// ---------------- fused attention, 512 threads (8 waves), 4 blocks/CU ----------------
// R5-proven config: launch_bounds(512,8), joint radix, per-row pass A/B.
#define SSTR 1036
__global__ __launch_bounds__(512, 8) void attn_kernel(const u16* __restrict__ qb,
                                                      const u16* __restrict__ kb,
                                                      const u16* __restrict__ vb,
                                                      const int* __restrict__ mask,
                                                      u16* __restrict__ xout) {
  extern __shared__ __align__(16) char smem[];
  u16* Sb = reinterpret_cast<u16*>(smem);                               // 33152 B
  u16* qs = reinterpret_cast<u16*>(smem + 33152);                       // 2304 B
  unsigned char* mk8 = reinterpret_cast<unsigned char*>(smem + 35456);  // 1024 B
  float* invZs = reinterpret_cast<float*>(smem + 36480);                // 64 B
  float* part = reinterpret_cast<float*>(smem + 36544);                 // 4096 B

  int blk = blockIdx.x;
  int bh = blk >> 6, qt = blk & 63;
  int b = bh >> 4, h = bh & 15;
  int t = threadIdx.x, wave = t >> 6, lane = t & 63;
  const u16* qh = qb + ((size_t)bh * 1024 + qt * 16) * 64;
  const u16* kh = kb + (size_t)bh * 65536;  // fragment-major
  const u16* vh = vb + (size_t)bh * 65536;  // fragment-major

  {
    int2 mm = *reinterpret_cast<const int2*>(mask + b * 1024 + t * 2);
    u16 pk = (u16)((mm.x != 0 ? 1u : 0u) | ((mm.y != 0 ? 1u : 0u) << 8));
    *reinterpret_cast<u16*>(&mk8[t * 2]) = pk;
  }
  if (t < 256) {
    int row = t >> 4, c4 = (t & 15) * 4;
    *reinterpret_cast<ushort4*>(&qs[row * 72 + c4]) =
        *reinterpret_cast<const ushort4*>(qh + row * 64 + c4);
  }
  __syncthreads();

  int lrow = lane & 15, lko = (lane >> 4) * 8;
  int quad = lane >> 4;
  int dtile = wave & 3, kq = wave >> 2;
  const u16* vbase = vh + (size_t)(kq * 16 * 4 + dtile) * 512 + lane * 8;

  // phase 1: scores^T tiles (A = K-frag, B = Q-frag); 8 k-tiles per wave.
  {
    short8 qf0 = *reinterpret_cast<const short8*>(&qs[lrow * 72 + lko]);
    short8 qf1 = *reinterpret_cast<const short8*>(&qs[lrow * 72 + lko + 32]);
#pragma unroll 4
    for (int c = 0; c < 8; ++c) {
      int kc = wave * 8 + c;
      const u16* kt = kh + (size_t)kc * 1024 + lane * 8;
      short8 kf0 = *reinterpret_cast<const short8*>(kt);
      short8 kf1 = *reinterpret_cast<const short8*>(kt + 512);
      floatx4 acc = (floatx4){0.f, 0.f, 0.f, 0.f};
      acc = __builtin_amdgcn_mfma_f32_16x16x32_bf16(kf0, qf0, acc, 0, 0, 0);
      acc = __builtin_amdgcn_mfma_f32_16x16x32_bf16(kf1, qf1, acc, 0, 0, 0);
      unsigned kk[4];
#pragma unroll
      for (int i = 0; i < 4; ++i) {
        float f = __builtin_fmaf(acc[i], 64.f, 4096.f);
        f = __builtin_amdgcn_fmed3f(f, 0.f, 8191.f);  // clamp in one op
        kk[i] = (unsigned)f;
      }
      uint2 pk;
      pk.x = __builtin_amdgcn_perm(kk[1], kk[0], 0x05040100u);  // kk0 | kk1<<16
      pk.y = __builtin_amdgcn_perm(kk[3], kk[2], 0x05040100u);
      *reinterpret_cast<uint2*>(&Sb[lrow * SSTR + kc * 16 + quad * 4]) = pk;
    }
  }
  __syncthreads();

  // V prefetch: first 4 fragments for this wave's (dtile,kq); latency hides under phase 2.
  short8 vp0 = *reinterpret_cast<const short8*>(vbase);
  short8 vp1 = *reinterpret_cast<const short8*>(vbase + 2048);
  short8 vp2 = *reinterpret_cast<const short8*>(vbase + 4096);
  short8 vp3 = *reinterpret_cast<const short8*>(vbase + 6144);
  asm volatile("" : "+v"(vp0), "+v"(vp1), "+v"(vp2), "+v"(vp3));

  // phase 2: JOINT radix for rows 2w and 2w+1.
  {
    const u16* SrA = Sb + (wave * 2) * SSTR;
    const u16* SrB = Sb + (wave * 2 + 1) * SSTR;
    unsigned kA[16], kB[16];
#pragma unroll
    for (int jj = 0; jj < 4; ++jj) {
      uint2 pa = *reinterpret_cast<const uint2*>(SrA + 4 * lane + 256 * jj);
      uint2 pb = *reinterpret_cast<const uint2*>(SrB + 4 * lane + 256 * jj);
      kA[4 * jj + 0] = pa.x & 0xffffu; kA[4 * jj + 1] = pa.x >> 16;
      kA[4 * jj + 2] = pa.y & 0xffffu; kA[4 * jj + 3] = pa.y >> 16;
      kB[4 * jj + 0] = pb.x & 0xffffu; kB[4 * jj + 1] = pb.x >> 16;
      kB[4 * jj + 2] = pb.y & 0xffffu; kB[4 * jj + 3] = pb.y >> 16;
    }
    unsigned TA = 0, TB = 0;
    int dA = 0, dB = 0;
    for (int bit = 12; bit >= 5; --bit) {
      unsigned cA = TA | (1u << bit), cB = TB | (1u << bit);
      int cntA = 0, cntB = 0;
#pragma unroll
      for (int i = 0; i < 16; ++i) {
        cntA += (int)__popcll(__ballot(kA[i] >= cA));
        cntB += (int)__popcll(__ballot(kB[i] >= cB));
      }
      if (!dA && cntA >= TOPK_) { TA = cA; if (cntA == TOPK_) dA = 1; }
      if (!dB && cntB >= TOPK_) { TB = cB; if (cntB == TOPK_) dB = 1; }
      if (dA && dB) break;
    }
    // mask words are row-invariant: load once for both rows
    unsigned mm[4];
#pragma unroll
    for (int jj = 0; jj < 4; ++jj)
      mm[jj] = *reinterpret_cast<const unsigned*>(mk8 + 4 * lane + 256 * jj);
    const float C1 = 1.44269504f / 512.f;
    const float C0 = -4096.f * (1.44269504f / 512.f);
#pragma unroll 1
    for (int rr = 0; rr < 2; ++rr) {
      int row = wave * 2 + rr;
      unsigned T = rr ? TB : TA;
      unsigned kk[16];
      if (rr == 0) {
#pragma unroll
        for (int i = 0; i < 16; ++i) kk[i] = kA[i];
      } else {
        const u16* Sr = Sb + row * SSTR;
#pragma unroll
        for (int jj = 0; jj < 4; ++jj) {
          uint2 p = *reinterpret_cast<const uint2*>(Sr + 4 * lane + 256 * jj);
          kk[4 * jj + 0] = p.x & 0xffffu; kk[4 * jj + 1] = p.x >> 16;
          kk[4 * jj + 2] = p.y & 0xffffu; kk[4 * jj + 3] = p.y >> 16;
        }
      }
      float e[16];
      float seq[4] = {0.f, 0.f, 0.f, 0.f};
#pragma unroll
      for (int i = 0; i < 16; ++i) {
        float ex = __builtin_amdgcn_exp2f(__builtin_fmaf((float)kk[i], C1, C0));
        ex = (kk[i] >= T) ? ex : 0.f;
        e[i] = ex;
        seq[i & 3] += ex;
      }
      float se = wave_sum_f32((seq[0] + seq[1]) + (seq[2] + seq[3]));
      float cB2 = __builtin_amdgcn_rcpf(se) * 1.44269504f;
      float Z = 0.f;
      u16* Wr = Sb + row * SSTR;
#pragma unroll
      for (int jj = 0; jj < 4; ++jj) {
        unsigned m = mm[jj];
        float w0 = __builtin_amdgcn_exp2f(e[4 * jj + 0] * cB2);
        float w1 = __builtin_amdgcn_exp2f(e[4 * jj + 1] * cB2);
        float w2 = __builtin_amdgcn_exp2f(e[4 * jj + 2] * cB2);
        float w3 = __builtin_amdgcn_exp2f(e[4 * jj + 3] * cB2);
        w0 = (m & 0x000000ffu) ? 0.f : w0;
        w1 = (m & 0x0000ff00u) ? 0.f : w1;
        w2 = (m & 0x00ff0000u) ? 0.f : w2;
        w3 = (m & 0xff000000u) ? 0.f : w3;
        Z += (w0 + w1) + (w2 + w3);
        uint2 pw;
        pw.x = __builtin_amdgcn_perm(__builtin_bit_cast(unsigned, w1),
                                     __builtin_bit_cast(unsigned, w0), 0x07060302u);
        pw.y = __builtin_amdgcn_perm(__builtin_bit_cast(unsigned, w3),
                                     __builtin_bit_cast(unsigned, w2), 0x07060302u);
        *reinterpret_cast<uint2*>(Wr + 4 * lane + 256 * jj) = pw;
      }
      Z = wave_sum_f32(Z);
      if (lane == 0) invZs[row] = __builtin_amdgcn_rcpf(Z);
    }
  }
  __syncthreads();

  // phase 3: x = w @ v, K split 2 ways; wave = kq*4 + dtile.
  {
    floatx4 acc = (floatx4){0.f, 0.f, 0.f, 0.f};
    const u16* wrow = Sb + lrow * SSTR + kq * 512;
    short8 af;
    af = *reinterpret_cast<const short8*>(wrow + 0 * 32 + lko);
    acc = __builtin_amdgcn_mfma_f32_16x16x32_bf16(af, vp0, acc, 0, 0, 0);
    af = *reinterpret_cast<const short8*>(wrow + 1 * 32 + lko);
    acc = __builtin_amdgcn_mfma_f32_16x16x32_bf16(af, vp1, acc, 0, 0, 0);
    af = *reinterpret_cast<const short8*>(wrow + 2 * 32 + lko);
    acc = __builtin_amdgcn_mfma_f32_16x16x32_bf16(af, vp2, acc, 0, 0, 0);
    af = *reinterpret_cast<const short8*>(wrow + 3 * 32 + lko);
    acc = __builtin_amdgcn_mfma_f32_16x16x32_bf16(af, vp3, acc, 0, 0, 0);
#pragma unroll
    for (int ks = 4; ks < 16; ++ks) {
      short8 bf = *reinterpret_cast<const short8*>(vbase + (size_t)ks * 2048);
      short8 af2 = *reinterpret_cast<const short8*>(wrow + ks * 32 + lko);
      acc = __builtin_amdgcn_mfma_f32_16x16x32_bf16(af2, bf, acc, 0, 0, 0);
    }
    if (kq == 1)
      *reinterpret_cast<floatx4*>(part + (size_t)(dtile * 64 + lane) * 4) = acc;
    __syncthreads();
    if (kq == 0) {
      floatx4 p2 = *reinterpret_cast<const floatx4*>(part + (size_t)(dtile * 64 + lane) * 4);
      float4 iz = *reinterpret_cast<const float4*>(&invZs[quad * 4]);
      int d = dtile * 16 + lrow;
      u16* xo = xout + ((size_t)(b * 1024 + qt * 16 + quad * 4)) * 1024 + h * 64 + d;
      xo[0 * 1024] = f2bf((acc[0] + p2[0]) * iz.x);
      xo[1 * 1024] = f2bf((acc[1] + p2[1]) * iz.y);
      xo[2 * 1024] = f2bf((acc[2] + p2[2]) * iz.z);
      xo[3 * 1024] = f2bf((acc[3] + p2[3]) * iz.w);
    }
  }
}

// ---------------- residual + layernorm + fused sim: ONE WAVE PER ROW ----------------
__global__ void resid_ln(const u16* __restrict__ y,
                         const float* __restrict__ text,
                         const float* __restrict__ g,
                         const float* __restrict__ be,
                         const float* __restrict__ vhat,
                         const int* __restrict__ mask,
                         const float* __restrict__ alpha,
                         const float* __restrict__ beta,
                         float* __restrict__ tf,
                         float* __restrict__ sim_g) {
  int wave = threadIdx.x >> 6, lane = threadIdx.x & 63;
  int row = blockIdx.x * 8 + wave;
  int b = row >> 10;
  size_t rbase = (size_t)row * 1024;
  int c0 = lane * 4;
  float v[16];
  float s = 0.f, sq = 0.f;
#pragma unroll
  for (int i = 0; i < 4; ++i) {
    float4 tv = *reinterpret_cast<const float4*>(text + rbase + i * 256 + c0);
    ushort4 yv = *reinterpret_cast<const ushort4*>(y + rbase + i * 256 + c0);
    float a0 = bf2f(yv.x) + tv.x;
    float a1 = bf2f(yv.y) + tv.y;
    float a2 = bf2f(yv.z) + tv.z;
    float a3 = bf2f(yv.w) + tv.w;
    v[i * 4 + 0] = a0; v[i * 4 + 1] = a1; v[i * 4 + 2] = a2; v[i * 4 + 3] = a3;
    s += (a0 + a1) + (a2 + a3);
    sq += (a0 * a0 + a1 * a1) + (a2 * a2 + a3 * a3);
  }
  wave_sum2_f32(s, sq);
  float mean = s * (1.f / 1024.f);
  float var = sq * (1.f / 1024.f) - mean * mean;
  float rs = rsqrtf(var + 1e-5f);
  float s2 = 0.f, dd = 0.f;
#pragma unroll
  for (int i = 0; i < 4; ++i) {
    float4 gv = *reinterpret_cast<const float4*>(g + i * 256 + c0);
    float4 bv = *reinterpret_cast<const float4*>(be + i * 256 + c0);
    float4 hv = *reinterpret_cast<const float4*>(vhat + b * 1024 + i * 256 + c0);
    float o0 = (v[i * 4 + 0] - mean) * rs * gv.x + bv.x;
    float o1 = (v[i * 4 + 1] - mean) * rs * gv.y + bv.y;
    float o2 = (v[i * 4 + 2] - mean) * rs * gv.z + bv.z;
    float o3 = (v[i * 4 + 3] - mean) * rs * gv.w + bv.w;
    float4 ov = make_float4(o0, o1, o2, o3);
    *reinterpret_cast<float4*>(tf + rbase + i * 256 + c0) = ov;
    s2 += (o0 * o0 + o1 * o1) + (o2 * o2 + o3 * o3);
    dd += (o0 * hv.x + o1 * hv.y) + (o2 * hv.z + o3 * hv.w);
  }
  wave_sum2_f32(s2, dd);
  if (lane == 0) {
    float den = fmaxf(sqrtf(s2), 1e-12f);
    float sv = beta[0] + alpha[0] * dd / den;
    sim_g[row] = mask[row] ? -__builtin_inff() : sv;
  }
}

// ---------------- top-256 of sim + partial pooled sum (atomic) ----------------
__global__ __launch_bounds__(256) void topk_pool(const float* __restrict__ sim_g,
                                                 const float* __restrict__ tf,
                                                 float* __restrict__ ttpre_acc) {
  __shared__ int idxl[256];
  __shared__ int scount;
  int b = blockIdx.x, p = blockIdx.y, t = threadIdx.x, lane = t & 63;
  if (t == 0) scount = 0;
  __syncthreads();
  if (t < 64) {
    unsigned uv[16];
#pragma unroll
    for (int j = 0; j < 16; ++j) {
      unsigned x = __builtin_bit_cast(unsigned, sim_g[b * 1024 + lane + 64 * j]);
      uv[j] = (x & 0x80000000u) ? ~x : (x | 0x80000000u);
    }
    unsigned T = 0;
    for (int bit = 31; bit >= 0; --bit) {
      unsigned cand = T | (1u << bit);
      int c = 0;
#pragma unroll
      for (int j = 0; j < 16; ++j) c += __popcll(__ballot(uv[j] >= cand));
      if (c >= TOPK_) {
        T = cand;
        if (c == TOPK_) break;
      }
    }
#pragma unroll
    for (int j = 0; j < 16; ++j) {
      if (uv[j] >= T) {
        int q = atomicAdd(&scount, 1);
        if (q < TOPK_) idxl[q] = lane + 64 * j;
      }
    }
  }
  __syncthreads();
  float4 pa = make_float4(0.f, 0.f, 0.f, 0.f);
  for (int i = p * 64; i < p * 64 + 64; ++i) {
    int n = idxl[i];
    float4 vr = *reinterpret_cast<const float4*>(tf + ((size_t)b * 1024 + n) * 1024 + t * 4);
    pa.x += vr.x; pa.y += vr.y; pa.z += vr.z; pa.w += vr.w;
  }
  atomicAdd(&ttpre_acc[b * 1024 + t * 4 + 0], pa.x);
  atomicAdd(&ttpre_acc[b * 1024 + t * 4 + 1], pa.y);
  atomicAdd(&ttpre_acc[b * 1024 + t * 4 + 2], pa.z);
  atomicAdd(&ttpre_acc[b * 1024 + t * 4 + 3], pa.w);
}

// ---------------- ttv = (pool/256 + txt) @ Wp1 + bp1, grid (8,16) ----------------
__global__ __launch_bounds__(256) void matvec_p1(const float* __restrict__ ttpre_acc,
                                                 const float* __restrict__ txt,
                                                 const float* __restrict__ Wp1,
                                                 const float* __restrict__ bp1,
                                                 float* __restrict__ ttv) {
  __shared__ float xs[1024];
  __shared__ float red[4][64];
  int b = blockIdx.x, q = blockIdx.y, t = threadIdx.x;
  for (int j = t; j < 1024; j += 256)
    xs[j] = ttpre_acc[b * 1024 + j] * (1.f / 256.f) + txt[b * 1024 + j];
  __syncthreads();
  int r = t >> 6, col = q * 64 + (t & 63);
  float acc = 0.f;
#pragma unroll 8
  for (int c = r * 256; c < r * 256 + 256; ++c) acc += xs[c] * Wp1[(size_t)c * 1024 + col];
  red[r][t & 63] = acc;
  __syncthreads();
  if (t < 64) {
    float o = red[0][t] + red[1][t] + red[2][t] + red[3][t] + bp1[q * 64 + t];
    ttv[b * 1024 + q * 64 + t] = o;
  }
}

// ---------------- final LN over ttv ----------------
__global__ __launch_bounds__(256) void ln_tt(const float* __restrict__ ttv,
                                             const float* __restrict__ g1,
                                             const float* __restrict__ b1,
                                             float* __restrict__ tt_out) {
  __shared__ float red[4];
  int b = blockIdx.x, t = threadIdx.x, wave = t >> 6, lane = t & 63;
  float4 v = *reinterpret_cast<const float4*>(ttv + b * 1024 + t * 4);
  float s = v.x + v.y + v.z + v.w;
  float sq = v.x * v.x + v.y * v.y + v.z * v.z + v.w * v.w;
  s = block_sum256(s, red, wave, lane);
  sq = block_sum256(sq, red, wave, lane);
  float mean = s * (1.f / 1024.f);
  float var = sq * (1.f / 1024.f) - mean * mean;
  float rs = rsqrtf(var + 1e-5f);
  float4 gv = *reinterpret_cast<const float4*>(g1 + t * 4);
  float4 bv = *reinterpret_cast<const float4*>(b1 + t * 4);
  float4 o;
  o.x = (v.x - mean) * rs * gv.x + bv.x;
  o.y = (v.y - mean) * rs * gv.y + bv.y;
  o.z = (v.z - mean) * rs * gv.z + bv.z;
  o.w = (v.w - mean) * rs * gv.w + bv.w;
  *reinterpret_cast<float4*>(tt_out + b * 1024 + t * 4) = o;
}

extern "C" void kernel_launch(void* const* d_in, const int* in_sizes, int n_in, void* d_out,
                              int out_size, void* d_ws, size_t ws_size, hipStream_t stream) {
  (void)in_sizes; (void)n_in; (void)out_size; (void)ws_size;
  const float* txt = (const float*)d_in[0];
  const float* text = (const float*)d_in[1];
  const int* mask = (const int*)d_in[2];
  const float* vis = (const float*)d_in[3];
  const float* Wqkv = (const float*)d_in[5];
  const float* bqkv = (const float*)d_in[6];
  const float* Wp2 = (const float*)d_in[7];
  const float* bp2 = (const float*)d_in[8];
  const float* g2 = (const float*)d_in[9];
  const float* b2 = (const float*)d_in[10];
  const float* alpha = (const float*)d_in[11];
  const float* beta = (const float*)d_in[12];
  const float* Wp1 = (const float*)d_in[13];
  const float* bp1 = (const float*)d_in[14];
  const float* g1 = (const float*)d_in[15];
  const float* b1 = (const float*)d_in[16];

  char* ws = (char*)d_ws;
  const size_t MB = 1u << 20;
  u16* Abf = (u16*)(ws);               // 16 MB; reused as attn-x buffer
  u16* Wtqkv = (u16*)(ws + 16 * MB);   // 6 MB
  u16* Wtp2 = (u16*)(ws + 22 * MB);    // 2 MB
  u16* qbuf = (u16*)(ws + 24 * MB);    // 16 MB
  u16* kbuf = (u16*)(ws + 40 * MB);    // 16 MB  fragment-major
  u16* vbuf = (u16*)(ws + 56 * MB);    // 16 MB  fragment-major
  u16* ybuf = (u16*)(ws + 72 * MB);    // 16 MB bf16 y
  float* vhat = (float*)(ws + 88 * MB);            // 32 KB
  float* sim_g = (float*)(ws + 88 * MB + 65536);   // 32 KB
  float* ttpre = (float*)(ws + 88 * MB + 131072);  // 32 KB
  float* ttv = (float*)(ws + 88 * MB + 196608);    // 32 KB

  float* out = (float*)d_out;
  float* tt_out = out;             // 8*1024
  float* tf_out = out + 8 * 1024;  // 8*1024*1024

  hipMemsetAsync(ttpre, 0, 8 * 1024 * sizeof(float), stream);
  prep_kernel<<<dim3(12296), dim3(256), 0, stream>>>(text, Abf, Wqkv, Wtqkv, Wp2, Wtp2, vis,
                                                     vhat);
  gemm_bt<<<dim3(24, 64), dim3(256), 0, stream>>>(Abf, Wtqkv, bqkv, 8192, 3072, 1024, 0, qbuf,
                                                  kbuf, vbuf, (u16*)nullptr);
  attn_kernel<<<dim3(8192), dim3(512), 40640, stream>>>(qbuf, kbuf, vbuf, mask, Abf);
  gemm_bt<<<dim3(8, 64), dim3(256), 0, stream>>>(Abf, Wtp2, bp2, 8192, 1024, 1024, 1,
                                                 (u16*)nullptr, (u16*)nullptr, (u16*)nullptr,
                                                 ybuf);
  resid_ln<<<dim3(1024), dim3(512), 0, stream>>>(ybuf, text, g2, b2, vhat, mask, alpha, beta,
                                                 tf_out, sim_g);
  topk_pool<<<dim3(8, 4), dim3(256), 0, stream>>>(sim_g, tf_out, ttpre);
  matvec_p1<<<dim3(8, 16), dim3(256), 0, stream>>>(ttpre, txt, Wp1, bp1, ttv);
  ln_tt<<<dim3(8), dim3(256), 0, stream>>>(ttv, g1, b1, tt_out);
}

// Round 10
// 425.856 us; speedup vs baseline: 1.0966x; 1.0272x over previous
//
#include <hip/hip_runtime.h>
#include <stdint.h>

typedef unsigned short u16;
typedef float floatx4 __attribute__((ext_vector_type(4)));
typedef short short8 __attribute__((ext_vector_type(8)));

#define TOPK_ 256

#define AS1(p) ((const __attribute__((address_space(1))) void*)(p))
#define AS3(p) ((__attribute__((address_space(3))) void*)(p))

__device__ __forceinline__ u16 f2bf(float f) {
  unsigned u = __builtin_bit_cast(unsigned, f);
  unsigned r = (u + 0x7FFFu + ((u >> 16) & 1u)) >> 16;
  return (u16)r;
}
__device__ __forceinline__ float bf2f(u16 b) {
  unsigned u = ((unsigned)b) << 16;
  return __builtin_bit_cast(float, u);
}

// ---- DPP wave-64 sum, result uniform via readlane ----
__device__ __forceinline__ float wave_sum_f32(float x) {
#define DPP_STEP(ctrl, rmask)                                                        \
  {                                                                                  \
    float t_ = __builtin_bit_cast(                                                   \
        float, __builtin_amdgcn_update_dpp(0, __builtin_bit_cast(int, x), ctrl,      \
                                           rmask, 0xf, true));                       \
    x += t_;                                                                         \
  }
  DPP_STEP(0x111, 0xf)
  DPP_STEP(0x112, 0xf)
  DPP_STEP(0x114, 0xf)
  DPP_STEP(0x118, 0xf)
  DPP_STEP(0x142, 0xa)
  DPP_STEP(0x143, 0xc)
#undef DPP_STEP
  return __builtin_bit_cast(float,
                            __builtin_amdgcn_readlane(__builtin_bit_cast(int, x), 63));
}

// ---- two independent wave sums, DPP chains interleaved for ILP ----
__device__ __forceinline__ void wave_sum2_f32(float& x, float& y) {
#define DPP_STEP2(ctrl, rmask)                                                       \
  {                                                                                  \
    float tx_ = __builtin_bit_cast(                                                  \
        float, __builtin_amdgcn_update_dpp(0, __builtin_bit_cast(int, x), ctrl,      \
                                           rmask, 0xf, true));                       \
    float ty_ = __builtin_bit_cast(                                                  \
        float, __builtin_amdgcn_update_dpp(0, __builtin_bit_cast(int, y), ctrl,      \
                                           rmask, 0xf, true));                       \
    x += tx_;                                                                        \
    y += ty_;                                                                        \
  }
  DPP_STEP2(0x111, 0xf)
  DPP_STEP2(0x112, 0xf)
  DPP_STEP2(0x114, 0xf)
  DPP_STEP2(0x118, 0xf)
  DPP_STEP2(0x142, 0xa)
  DPP_STEP2(0x143, 0xc)
#undef DPP_STEP2
  x = __builtin_bit_cast(float, __builtin_amdgcn_readlane(__builtin_bit_cast(int, x), 63));
  y = __builtin_bit_cast(float, __builtin_amdgcn_readlane(__builtin_bit_cast(int, y), 63));
}

// ---------------- block-wide sum over 256 threads ----------------
__device__ __forceinline__ float block_sum256(float v, volatile float* scratch, int wave,
                                              int lane) {
#pragma unroll
  for (int o = 32; o > 0; o >>= 1) v += __shfl_xor(v, o);
  __syncthreads();
  if (lane == 0) scratch[wave] = v;
  __syncthreads();
  return scratch[0] + scratch[1] + scratch[2] + scratch[3];
}

// ---------------- fused prep: cast + weight transposes + vhat + ttpre zero ----------------
// grid: [0,8192) cast text->bf16; [8192,11264) Wqkv transpose; [11264,12288) Wp2
// transpose; [12288,12296) vhat; 12296 zeroes ttpre (replaces hipMemsetAsync launch).
__global__ __launch_bounds__(256) void prep_kernel(const float* __restrict__ text,
                                                   u16* __restrict__ Abf,
                                                   const float* __restrict__ Wqkv,
                                                   u16* __restrict__ Wtqkv,
                                                   const float* __restrict__ Wp2,
                                                   u16* __restrict__ Wtp2,
                                                   const float* __restrict__ vis,
                                                   float* __restrict__ vhat,
                                                   float* __restrict__ ttpre) {
  __shared__ u16 tile[32][33];
  __shared__ float red[4];
  int blk = blockIdx.x, t = threadIdx.x;
  if (blk < 8192) {
    int i = (blk * 256 + t) * 4;
    float4 v = *reinterpret_cast<const float4*>(text + i);
    ushort4 o;
    o.x = f2bf(v.x); o.y = f2bf(v.y); o.z = f2bf(v.z); o.w = f2bf(v.w);
    *reinterpret_cast<ushort4*>(Abf + i) = o;
  } else if (blk < 12288) {
    const float* W;
    u16* Wt;
    int cols, id;
    if (blk < 11264) { W = Wqkv; Wt = Wtqkv; cols = 3072; id = blk - 8192; }
    else             { W = Wp2;  Wt = Wtp2;  cols = 1024; id = blk - 11264; }
    int nx = cols >> 5;
    int n0 = (id % nx) * 32, k0 = (id / nx) * 32;
    int r = t >> 3, c4 = (t & 7) * 4;
    float4 v = *reinterpret_cast<const float4*>(W + (size_t)(k0 + r) * cols + n0 + c4);
    tile[r][c4 + 0] = f2bf(v.x);
    tile[r][c4 + 1] = f2bf(v.y);
    tile[r][c4 + 2] = f2bf(v.z);
    tile[r][c4 + 3] = f2bf(v.w);
    __syncthreads();
    ushort4 o;
    o.x = tile[c4 + 0][r]; o.y = tile[c4 + 1][r];
    o.z = tile[c4 + 2][r]; o.w = tile[c4 + 3][r];
    *reinterpret_cast<ushort4*>(Wt + (size_t)(n0 + r) * 1024 + k0 + c4) = o;
  } else if (blk < 12296) {
    int b = blk - 12288, wave = t >> 6, lane = t & 63;
    float4 vv = *reinterpret_cast<const float4*>(vis + b * 1024 + t * 4);
    float sq = vv.x * vv.x + vv.y * vv.y + vv.z * vv.z + vv.w * vv.w;
    sq = block_sum256(sq, red, wave, lane);
    float inv = 1.f / fmaxf(sqrtf(sq), 1e-12f);
    float4 o = make_float4(vv.x * inv, vv.y * inv, vv.z * inv, vv.w * inv);
    *reinterpret_cast<float4*>(vhat + b * 1024 + t * 4) = o;
  } else {
    float4 z = make_float4(0.f, 0.f, 0.f, 0.f);
#pragma unroll
    for (int j = 0; j < 8; ++j)
      reinterpret_cast<float4*>(ttpre)[t + j * 256] = z;
  }
}

// ---------------- bf16 GEMM, 128x128 tile, QUAD-buffered global_load_lds ----------------
// 4 LDS bufs (64KB), ONE barrier per K-step, counted vmcnt (never 0 in steady state).
// Hazard proof: with 1-barrier skew, concurrent waves span at most iters {kt-1, kt}.
// Stage target (kt+2)&3 differs from both read bufs (kt-1)&3 and kt&3; a reader of
// (kt-2)&3 (== (kt+2)&3) must have passed barrier(kt-1) first, and its ds_reads
// completed before that barrier (register consumption by MFMA) -> no overwrite race.
// vs R8's 3-buf/2-barrier: same prefetch depth (2 K-steps), half the barriers;
// trades occupancy 3->2 blocks/CU.
__global__ __launch_bounds__(256) void gemm_bt(const u16* __restrict__ A,
                                               const u16* __restrict__ Bt,
                                               const float* __restrict__ bias,
                                               int M, int Nn, int K, int mode,
                                               u16* __restrict__ qb, u16* __restrict__ kb,
                                               u16* __restrict__ vb, u16* __restrict__ yb) {
  __shared__ __align__(16) u16 SMEM[32768];  // 4 bufs x (A 4096 + B 4096) u16 = 64KB
  // XCD swizzle: dispatch-linear id -> chunked id so each XCD works a contiguous range
  int id = blockIdx.x + blockIdx.y * gridDim.x;
  int cpx = (gridDim.x * gridDim.y) >> 3;
  int swz = (id & 7) * cpx + (id >> 3);
  int bx = swz % gridDim.x, by = swz / gridDim.x;
  int m0 = by * 128, n0 = bx * 128;
  int t = threadIdx.x, lane = t & 63, wave = t >> 6;
  int wr = wave >> 1, wc = wave & 1;
  int lrow = lane & 15, lko = (lane >> 4) * 8;
  floatx4 acc[4][4];
#pragma unroll
  for (int i = 0; i < 4; ++i)
#pragma unroll
    for (int j = 0; j < 4; ++j) acc[i][j] = (floatx4){0.f, 0.f, 0.f, 0.f};
  int srow = t >> 2, sc8 = (t & 3) * 8;
  const u16* gA0 = A + (size_t)(m0 + srow) * K + sc8;
  const u16* gA1 = A + (size_t)(m0 + srow + 64) * K + sc8;
  const u16* gB0 = Bt + (size_t)(n0 + srow) * K + sc8;
  const u16* gB1 = Bt + (size_t)(n0 + srow + 64) * K + sc8;

#define STAGE_KT(ktv, bufv)                                                              \
  {                                                                                      \
    int koff_ = (ktv) * 32;                                                              \
    u16* dst_ = SMEM + (bufv) * 8192 + t * 8;                                            \
    __builtin_amdgcn_global_load_lds(AS1(gA0 + koff_), AS3(dst_), 16, 0, 0);             \
    __builtin_amdgcn_global_load_lds(AS1(gA1 + koff_), AS3(dst_ + 2048), 16, 0, 0);      \
    __builtin_amdgcn_global_load_lds(AS1(gB0 + koff_), AS3(dst_ + 4096), 16, 0, 0);      \
    __builtin_amdgcn_global_load_lds(AS1(gB1 + koff_), AS3(dst_ + 6144), 16, 0, 0);      \
  }

  // prologue: stage kt=0 (buf0) and kt=1 (buf1)
  STAGE_KT(0, 0)
  STAGE_KT(1, 1)
  const int NKT = 32;  // K/32 (K==1024 at both call sites)
#pragma unroll 1
  for (int kt = 0; kt < NKT; ++kt) {
    int kn = kt + 2;
    if (kn < NKT) STAGE_KT(kn, kn & 3)
    // wait: kt's 4 loads landed (per wave); kt+1/kt+2's 8 may stay in flight
    if (kt < NKT - 2)       asm volatile("s_waitcnt vmcnt(8)" ::: "memory");
    else if (kt == NKT - 2) asm volatile("s_waitcnt vmcnt(4)" ::: "memory");
    else                    asm volatile("s_waitcnt vmcnt(0)" ::: "memory");
    __builtin_amdgcn_s_barrier();
    const u16* Asb = SMEM + (kt & 3) * 8192;
    const u16* Bsb = Asb + 4096;
    short8 afr[4], bfr[4];
#pragma unroll
    for (int i = 0; i < 4; ++i) {
      afr[i] = *reinterpret_cast<const short8*>(&Asb[(wr * 64 + i * 16 + lrow) * 32 + lko]);
      bfr[i] = *reinterpret_cast<const short8*>(&Bsb[(wc * 64 + i * 16 + lrow) * 32 + lko]);
    }
#pragma unroll
    for (int i = 0; i < 4; ++i)
#pragma unroll
      for (int j = 0; j < 4; ++j)
        acc[i][j] = __builtin_amdgcn_mfma_f32_16x16x32_bf16(afr[i], bfr[j], acc[i][j], 0, 0, 0);
  }
#undef STAGE_KT

  int rb = (lane >> 4) * 4;
  if (mode == 0 && n0 >= 2048) {
    // V path: fragment-major store
#pragma unroll
    for (int i = 0; i < 4; ++i) {
#pragma unroll
      for (int j = 0; j < 4; ++j) {
        int gcol = n0 + wc * 64 + j * 16 + lrow;
        float bv = bias[gcol];
        int grow0 = m0 + wr * 64 + i * 16 + rb;
        int cc = gcol & 1023, hh = cc >> 6, dd = cc & 63;
        int bb = grow0 >> 10, nq0 = grow0 & 1023;
        size_t headq = ((size_t)bb * 16 + hh);
        int dtile = dd >> 4, drow = dd & 15;
        int ks32 = nq0 >> 5, kk = nq0 & 31, lq = kk >> 3, e = kk & 7;
        int lane2 = lq * 16 + drow;
        ushort4 o;
        o.x = f2bf(acc[i][j][0] + bv);
        o.y = f2bf(acc[i][j][1] + bv);
        o.z = f2bf(acc[i][j][2] + bv);
        o.w = f2bf(acc[i][j][3] + bv);
        *reinterpret_cast<ushort4*>(vb + headq * 65536 + (size_t)ks32 * 2048 +
                                    dtile * 512 + lane2 * 8 + e) = o;
      }
    }
  } else {
    u16* LDSC = SMEM;  // [128][72]
    for (int half = 0; half < 2; ++half) {
      __syncthreads();
      if (wc == half) {
#pragma unroll
        for (int i = 0; i < 4; ++i)
#pragma unroll
          for (int j = 0; j < 4; ++j) {
            float bv = bias[n0 + half * 64 + j * 16 + lrow];
#pragma unroll
            for (int rr = 0; rr < 4; ++rr)
              LDSC[(wr * 64 + i * 16 + rb + rr) * 72 + j * 16 + lrow] =
                  f2bf(acc[i][j][rr] + bv);
          }
      }
      __syncthreads();
      int row = t >> 4, c4 = (t & 15) * 4;
#pragma unroll
      for (int it = 0; it < 8; ++it) {
        int rw = row + it * 16;
        ushort4 val = *reinterpret_cast<const ushort4*>(&LDSC[rw * 72 + c4]);
        int grow = m0 + rw, gcol = n0 + half * 64 + c4;
        if (mode == 1) {
          *reinterpret_cast<ushort4*>(yb + (size_t)grow * 1024 + gcol) = val;
        } else {
          int sec = gcol >> 10, cc = gcol & 1023, hh = cc >> 6, dd = cc & 63;
          int bb = grow >> 10, nq = grow & 1023;
          size_t head = ((size_t)bb * 16 + hh);
          if (sec == 0) {
            *reinterpret_cast<ushort4*>(qb + (head * 1024 + nq) * 64 + dd) = val;
          } else {
            // K path: fragment-major store (4 consecutive d at fixed nq)
            int kc = nq >> 4, krow = nq & 15;
            int p = dd >> 5, quad = (dd >> 3) & 3, e = dd & 7;
            *reinterpret_cast<ushort4*>(kb + head * 65536 + (size_t)kc * 1024 +
                                        p * 512 + (quad * 16 + krow) * 8 + e) = val;
          }
        }
      }
    }
  }
}

// ---------------- fused attention, 512 threads (8 waves), 4 blocks/CU ----------------
// R5-proven config + branchless radix (s_cselect instead of scc-branch; always 8
// rounds — provably selects the identical key set, removes 16 serial branches).
#define SSTR 1036
__global__ __launch_bounds__(512, 8) void attn_kernel(const u16* __restrict__ qb,
                                                      const u16* __restrict__ kb,
                                                      const u16* __restrict__ vb,
                                                      const int* __restrict__ mask,
                                                      u16* __restrict__ xout) {
  extern __shared__ __align__(16) char smem[];
  u16* Sb = reinterpret_cast<u16*>(smem);                               // 33152 B
  u16* qs = reinterpret_cast<u16*>(smem + 33152);                       // 2304 B
  unsigned char* mk8 = reinterpret_cast<unsigned char*>(smem + 35456);  // 1024 B
  float* invZs = reinterpret_cast<float*>(smem + 36480);                // 64 B
  float* part = reinterpret_cast<float*>(smem + 36544);                 // 4096 B

  int blk = blockIdx.x;
  int bh = blk >> 6, qt = blk & 63;
  int b = bh >> 4, h = bh & 15;
  int t = threadIdx.x, wave = t >> 6, lane = t & 63;
  const u16* qh = qb + ((size_t)bh * 1024 + qt * 16) * 64;
  const u16* kh = kb + (size_t)bh * 65536;  // fragment-major
  const u16* vh = vb + (size_t)bh * 65536;  // fragment-major

  {
    int2 mm = *reinterpret_cast<const int2*>(mask + b * 1024 + t * 2);
    u16 pk = (u16)((mm.x != 0 ? 1u : 0u) | ((mm.y != 0 ? 1u : 0u) << 8));
    *reinterpret_cast<u16*>(&mk8[t * 2]) = pk;
  }
  if (t < 256) {
    int row = t >> 4, c4 = (t & 15) * 4;
    *reinterpret_cast<ushort4*>(&qs[row * 72 + c4]) =
        *reinterpret_cast<const ushort4*>(qh + row * 64 + c4);
  }
  __syncthreads();

  int lrow = lane & 15, lko = (lane >> 4) * 8;
  int quad = lane >> 4;
  int dtile = wave & 3, kq = wave >> 2;
  const u16* vbase = vh + (size_t)(kq * 16 * 4 + dtile) * 512 + lane * 8;

  // phase 1: scores^T tiles (A = K-frag, B = Q-frag); 8 k-tiles per wave.
  {
    short8 qf0 = *reinterpret_cast<const short8*>(&qs[lrow * 72 + lko]);
    short8 qf1 = *reinterpret_cast<const short8*>(&qs[lrow * 72 + lko + 32]);
#pragma unroll 4
    for (int c = 0; c < 8; ++c) {
      int kc = wave * 8 + c;
      const u16* kt = kh + (size_t)kc * 1024 + lane * 8;
      short8 kf0 = *reinterpret_cast<const short8*>(kt);
      short8 kf1 = *reinterpret_cast<const short8*>(kt + 512);
      floatx4 acc = (floatx4){0.f, 0.f, 0.f, 0.f};
      acc = __builtin_amdgcn_mfma_f32_16x16x32_bf16(kf0, qf0, acc, 0, 0, 0);
      acc = __builtin_amdgcn_mfma_f32_16x16x32_bf16(kf1, qf1, acc, 0, 0, 0);
      unsigned kk[4];
#pragma unroll
      for (int i = 0; i < 4; ++i) {
        float f = __builtin_fmaf(acc[i], 64.f, 4096.f);
        f = __builtin_amdgcn_fmed3f(f, 0.f, 8191.f);  // clamp in one op
        kk[i] = (unsigned)f;
      }
      uint2 pk;
      pk.x = __builtin_amdgcn_perm(kk[1], kk[0], 0x05040100u);  // kk0 | kk1<<16
      pk.y = __builtin_amdgcn_perm(kk[3], kk[2], 0x05040100u);
      *reinterpret_cast<uint2*>(&Sb[lrow * SSTR + kc * 16 + quad * 4]) = pk;
    }
  }
  __syncthreads();

  // V prefetch: first 4 fragments for this wave's (dtile,kq); latency hides under phase 2.
  short8 vp0 = *reinterpret_cast<const short8*>(vbase);
  short8 vp1 = *reinterpret_cast<const short8*>(vbase + 2048);
  short8 vp2 = *reinterpret_cast<const short8*>(vbase + 4096);
  short8 vp3 = *reinterpret_cast<const short8*>(vbase + 6144);
  asm volatile("" : "+v"(vp0), "+v"(vp1), "+v"(vp2), "+v"(vp3));

  // phase 2: JOINT branchless radix for rows 2w and 2w+1.
  {
    const u16* SrA = Sb + (wave * 2) * SSTR;
    const u16* SrB = Sb + (wave * 2 + 1) * SSTR;
    unsigned kA[16], kB[16];
#pragma unroll
    for (int jj = 0; jj < 4; ++jj) {
      uint2 pa = *reinterpret_cast<const uint2*>(SrA + 4 * lane + 256 * jj);
      uint2 pb = *reinterpret_cast<const uint2*>(SrB + 4 * lane + 256 * jj);
      kA[4 * jj + 0] = pa.x & 0xffffu; kA[4 * jj + 1] = pa.x >> 16;
      kA[4 * jj + 2] = pa.y & 0xffffu; kA[4 * jj + 3] = pa.y >> 16;
      kB[4 * jj + 0] = pb.x & 0xffffu; kB[4 * jj + 1] = pb.x >> 16;
      kB[4 * jj + 2] = pb.y & 0xffffu; kB[4 * jj + 3] = pb.y >> 16;
    }
    unsigned TA = 0, TB = 0;
#pragma unroll
    for (int bit = 12; bit >= 5; --bit) {
      unsigned cA = TA | (1u << bit), cB = TB | (1u << bit);
      int cntA = 0, cntB = 0;
#pragma unroll
      for (int i = 0; i < 16; ++i) {
        cntA += (int)__popcll(__ballot(kA[i] >= cA));
        cntB += (int)__popcll(__ballot(kB[i] >= cB));
      }
      TA = (cntA >= TOPK_) ? cA : TA;
      TB = (cntB >= TOPK_) ? cB : TB;
    }
    // mask words are row-invariant: load once for both rows
    unsigned mm[4];
#pragma unroll
    for (int jj = 0; jj < 4; ++jj)
      mm[jj] = *reinterpret_cast<const unsigned*>(mk8 + 4 * lane + 256 * jj);
    const float C1 = 1.44269504f / 512.f;
    const float C0 = -4096.f * (1.44269504f / 512.f);
#pragma unroll 1
    for (int rr = 0; rr < 2; ++rr) {
      int row = wave * 2 + rr;
      unsigned T = rr ? TB : TA;
      unsigned kk[16];
      if (rr == 0) {
#pragma unroll
        for (int i = 0; i < 16; ++i) kk[i] = kA[i];
      } else {
        // reload row B keys from LDS (still intact; row A's pass B only wrote row A)
        const u16* Sr = Sb + row * SSTR;
#pragma unroll
        for (int jj = 0; jj < 4; ++jj) {
          uint2 p = *reinterpret_cast<const uint2*>(Sr + 4 * lane + 256 * jj);
          kk[4 * jj + 0] = p.x & 0xffffu; kk[4 * jj + 1] = p.x >> 16;
          kk[4 * jj + 2] = p.y & 0xffffu; kk[4 * jj + 3] = p.y >> 16;
        }
      }
      // pass A: e = exp(s) for selected; se = sum (4-way ILP accumulators).
      float e[16];
      float seq[4] = {0.f, 0.f, 0.f, 0.f};
#pragma unroll
      for (int i = 0; i < 16; ++i) {
        float ex = __builtin_amdgcn_exp2f(__builtin_fmaf((float)kk[i], C1, C0));
        ex = (kk[i] >= T) ? ex : 0.f;
        e[i] = ex;
        seq[i & 3] += ex;
      }
      float se = wave_sum_f32((seq[0] + seq[1]) + (seq[2] + seq[3]));
      float cB2 = __builtin_amdgcn_rcpf(se) * 1.44269504f;
      // pass B: w = masked?0:exp2(e*cB); packed b64 writes; Z accumulated
      float Z = 0.f;
      u16* Wr = Sb + row * SSTR;
#pragma unroll
      for (int jj = 0; jj < 4; ++jj) {
        unsigned m = mm[jj];
        float w0 = __builtin_amdgcn_exp2f(e[4 * jj + 0] * cB2);
        float w1 = __builtin_amdgcn_exp2f(e[4 * jj + 1] * cB2);
        float w2 = __builtin_amdgcn_exp2f(e[4 * jj + 2] * cB2);
        float w3 = __builtin_amdgcn_exp2f(e[4 * jj + 3] * cB2);
        w0 = (m & 0x000000ffu) ? 0.f : w0;
        w1 = (m & 0x0000ff00u) ? 0.f : w1;
        w2 = (m & 0x00ff0000u) ? 0.f : w2;
        w3 = (m & 0xff000000u) ? 0.f : w3;
        Z += (w0 + w1) + (w2 + w3);
        uint2 pw;
        pw.x = __builtin_amdgcn_perm(__builtin_bit_cast(unsigned, w1),
                                     __builtin_bit_cast(unsigned, w0), 0x07060302u);
        pw.y = __builtin_amdgcn_perm(__builtin_bit_cast(unsigned, w3),
                                     __builtin_bit_cast(unsigned, w2), 0x07060302u);
        *reinterpret_cast<uint2*>(Wr + 4 * lane + 256 * jj) = pw;
      }
      Z = wave_sum_f32(Z);
      if (lane == 0) invZs[row] = __builtin_amdgcn_rcpf(Z);
    }
  }
  __syncthreads();

  // phase 3: x = w @ v, K split 2 ways; wave = kq*4 + dtile.
  {
    floatx4 acc = (floatx4){0.f, 0.f, 0.f, 0.f};
    const u16* wrow = Sb + lrow * SSTR + kq * 512;
    short8 af;
    af = *reinterpret_cast<const short8*>(wrow + 0 * 32 + lko);
    acc = __builtin_amdgcn_mfma_f32_16x16x32_bf16(af, vp0, acc, 0, 0, 0);
    af = *reinterpret_cast<const short8*>(wrow + 1 * 32 + lko);
    acc = __builtin_amdgcn_mfma_f32_16x16x32_bf16(af, vp1, acc, 0, 0, 0);
    af = *reinterpret_cast<const short8*>(wrow + 2 * 32 + lko);
    acc = __builtin_amdgcn_mfma_f32_16x16x32_bf16(af, vp2, acc, 0, 0, 0);
    af = *reinterpret_cast<const short8*>(wrow + 3 * 32 + lko);
    acc = __builtin_amdgcn_mfma_f32_16x16x32_bf16(af, vp3, acc, 0, 0, 0);
#pragma unroll
    for (int ks = 4; ks < 16; ++ks) {
      short8 bf = *reinterpret_cast<const short8*>(vbase + (size_t)ks * 2048);
      short8 af2 = *reinterpret_cast<const short8*>(wrow + ks * 32 + lko);
      acc = __builtin_amdgcn_mfma_f32_16x16x32_bf16(af2, bf, acc, 0, 0, 0);
    }
    if (kq == 1)
      *reinterpret_cast<floatx4*>(part + (size_t)(dtile * 64 + lane) * 4) = acc;
    __syncthreads();
    if (kq == 0) {
      floatx4 p2 = *reinterpret_cast<const floatx4*>(part + (size_t)(dtile * 64 + lane) * 4);
      float4 iz = *reinterpret_cast<const float4*>(&invZs[quad * 4]);
      int d = dtile * 16 + lrow;
      u16* xo = xout + ((size_t)(b * 1024 + qt * 16 + quad * 4)) * 1024 + h * 64 + d;
      xo[0 * 1024] = f2bf((acc[0] + p2[0]) * iz.x);
      xo[1 * 1024] = f2bf((acc[1] + p2[1]) * iz.y);
      xo[2 * 1024] = f2bf((acc[2] + p2[2]) * iz.z);
      xo[3 * 1024] = f2bf((acc[3] + p2[3]) * iz.w);
    }
  }
}

// ---------------- residual + layernorm + fused sim: ONE WAVE PER ROW ----------------
__global__ void resid_ln(const u16* __restrict__ y,
                         const float* __restrict__ text,
                         const float* __restrict__ g,
                         const float* __restrict__ be,
                         const float* __restrict__ vhat,
                         const int* __restrict__ mask,
                         const float* __restrict__ alpha,
                         const float* __restrict__ beta,
                         float* __restrict__ tf,
                         float* __restrict__ sim_g) {
  int wave = threadIdx.x >> 6, lane = threadIdx.x & 63;
  int row = blockIdx.x * 8 + wave;
  int b = row >> 10;
  size_t rbase = (size_t)row * 1024;
  int c0 = lane * 4;
  float v[16];
  float s = 0.f, sq = 0.f;
#pragma unroll
  for (int i = 0; i < 4; ++i) {
    float4 tv = *reinterpret_cast<const float4*>(text + rbase + i * 256 + c0);
    ushort4 yv = *reinterpret_cast<const ushort4*>(y + rbase + i * 256 + c0);
    float a0 = bf2f(yv.x) + tv.x;
    float a1 = bf2f(yv.y) + tv.y;
    float a2 = bf2f(yv.z) + tv.z;
    float a3 = bf2f(yv.w) + tv.w;
    v[i * 4 + 0] = a0; v[i * 4 + 1] = a1; v[i * 4 + 2] = a2; v[i * 4 + 3] = a3;
    s += (a0 + a1) + (a2 + a3);
    sq += (a0 * a0 + a1 * a1) + (a2 * a2 + a3 * a3);
  }
  wave_sum2_f32(s, sq);
  float mean = s * (1.f / 1024.f);
  float var = sq * (1.f / 1024.f) - mean * mean;
  float rs = rsqrtf(var + 1e-5f);
  float s2 = 0.f, dd = 0.f;
#pragma unroll
  for (int i = 0; i < 4; ++i) {
    float4 gv = *reinterpret_cast<const float4*>(g + i * 256 + c0);
    float4 bv = *reinterpret_cast<const float4*>(be + i * 256 + c0);
    float4 hv = *reinterpret_cast<const float4*>(vhat + b * 1024 + i * 256 + c0);
    float o0 = (v[i * 4 + 0] - mean) * rs * gv.x + bv.x;
    float o1 = (v[i * 4 + 1] - mean) * rs * gv.y + bv.y;
    float o2 = (v[i * 4 + 2] - mean) * rs * gv.z + bv.z;
    float o3 = (v[i * 4 + 3] - mean) * rs * gv.w + bv.w;
    float4 ov = make_float4(o0, o1, o2, o3);
    *reinterpret_cast<float4*>(tf + rbase + i * 256 + c0) = ov;
    s2 += (o0 * o0 + o1 * o1) + (o2 * o2 + o3 * o3);
    dd += (o0 * hv.x + o1 * hv.y) + (o2 * hv.z + o3 * hv.w);
  }
  wave_sum2_f32(s2, dd);
  if (lane == 0) {
    float den = fmaxf(sqrtf(s2), 1e-12f);
    float sv = beta[0] + alpha[0] * dd / den;
    sim_g[row] = mask[row] ? -__builtin_inff() : sv;
  }
}

// ---------------- top-256 of sim + partial pooled sum (atomic) ----------------
__global__ __launch_bounds__(256) void topk_pool(const float* __restrict__ sim_g,
                                                 const float* __restrict__ tf,
                                                 float* __restrict__ ttpre_acc) {
  __shared__ int idxl[256];
  __shared__ int scount;
  int b = blockIdx.x, p = blockIdx.y, t = threadIdx.x, lane = t & 63;
  if (t == 0) scount = 0;
  __syncthreads();
  if (t < 64) {
    unsigned uv[16];
#pragma unroll
    for (int j = 0; j < 16; ++j) {
      unsigned x = __builtin_bit_cast(unsigned, sim_g[b * 1024 + lane + 64 * j]);
      uv[j] = (x & 0x80000000u) ? ~x : (x | 0x80000000u);
    }
    unsigned T = 0;
    for (int bit = 31; bit >= 0; --bit) {
      unsigned cand = T | (1u << bit);
      int c = 0;
#pragma unroll
      for (int j = 0; j < 16; ++j) c += __popcll(__ballot(uv[j] >= cand));
      if (c >= TOPK_) {
        T = cand;
        if (c == TOPK_) break;
      }
    }
#pragma unroll
    for (int j = 0; j < 16; ++j) {
      if (uv[j] >= T) {
        int q = atomicAdd(&scount, 1);
        if (q < TOPK_) idxl[q] = lane + 64 * j;
      }
    }
  }
  __syncthreads();
  float4 pa = make_float4(0.f, 0.f, 0.f, 0.f);
  for (int i = p * 64; i < p * 64 + 64; ++i) {
    int n = idxl[i];
    float4 vr = *reinterpret_cast<const float4*>(tf + ((size_t)b * 1024 + n) * 1024 + t * 4);
    pa.x += vr.x; pa.y += vr.y; pa.z += vr.z; pa.w += vr.w;
  }
  atomicAdd(&ttpre_acc[b * 1024 + t * 4 + 0], pa.x);
  atomicAdd(&ttpre_acc[b * 1024 + t * 4 + 1], pa.y);
  atomicAdd(&ttpre_acc[b * 1024 + t * 4 + 2], pa.z);
  atomicAdd(&ttpre_acc[b * 1024 + t * 4 + 3], pa.w);
}

// ---------------- ttv = (pool/256 + txt) @ Wp1 + bp1, grid (8,16) ----------------
__global__ __launch_bounds__(256) void matvec_p1(const float* __restrict__ ttpre_acc,
                                                 const float* __restrict__ txt,
                                                 const float* __restrict__ Wp1,
                                                 const float* __restrict__ bp1,
                                                 float* __restrict__ ttv) {
  __shared__ float xs[1024];
  __shared__ float red[4][64];
  int b = blockIdx.x, q = blockIdx.y, t = threadIdx.x;
  for (int j = t; j < 1024; j += 256)
    xs[j] = ttpre_acc[b * 1024 + j] * (1.f / 256.f) + txt[b * 1024 + j];
  __syncthreads();
  int r = t >> 6, col = q * 64 + (t & 63);
  float acc = 0.f;
#pragma unroll 8
  for (int c = r * 256; c < r * 256 + 256; ++c) acc += xs[c] * Wp1[(size_t)c * 1024 + col];
  red[r][t & 63] = acc;
  __syncthreads();
  if (t < 64) {
    float o = red[0][t] + red[1][t] + red[2][t] + red[3][t] + bp1[q * 64 + t];
    ttv[b * 1024 + q * 64 + t] = o;
  }
}

// ---------------- final LN over ttv ----------------
__global__ __launch_bounds__(256) void ln_tt(const float* __restrict__ ttv,
                                             const float* __restrict__ g1,
                                             const float* __restrict__ b1,
                                             float* __restrict__ tt_out) {
  __shared__ float red[4];
  int b = blockIdx.x, t = threadIdx.x, wave = t >> 6, lane = t & 63;
  float4 v = *reinterpret_cast<const float4*>(ttv + b * 1024 + t * 4);
  float s = v.x + v.y + v.z + v.w;
  float sq = v.x * v.x + v.y * v.y + v.z * v.z + v.w * v.w;
  s = block_sum256(s, red, wave, lane);
  sq = block_sum256(sq, red, wave, lane);
  float mean = s * (1.f / 1024.f);
  float var = sq * (1.f / 1024.f) - mean * mean;
  float rs = rsqrtf(var + 1e-5f);
  float4 gv = *reinterpret_cast<const float4*>(g1 + t * 4);
  float4 bv = *reinterpret_cast<const float4*>(b1 + t * 4);
  float4 o;
  o.x = (v.x - mean) * rs * gv.x + bv.x;
  o.y = (v.y - mean) * rs * gv.y + bv.y;
  o.z = (v.z - mean) * rs * gv.z + bv.z;
  o.w = (v.w - mean) * rs * gv.w + bv.w;
  *reinterpret_cast<float4*>(tt_out + b * 1024 + t * 4) = o;
}

extern "C" void kernel_launch(void* const* d_in, const int* in_sizes, int n_in, void* d_out,
                              int out_size, void* d_ws, size_t ws_size, hipStream_t stream) {
  (void)in_sizes; (void)n_in; (void)out_size; (void)ws_size;
  const float* txt = (const float*)d_in[0];
  const float* text = (const float*)d_in[1];
  const int* mask = (const int*)d_in[2];
  const float* vis = (const float*)d_in[3];
  const float* Wqkv = (const float*)d_in[5];
  const float* bqkv = (const float*)d_in[6];
  const float* Wp2 = (const float*)d_in[7];
  const float* bp2 = (const float*)d_in[8];
  const float* g2 = (const float*)d_in[9];
  const float* b2 = (const float*)d_in[10];
  const float* alpha = (const float*)d_in[11];
  const float* beta = (const float*)d_in[12];
  const float* Wp1 = (const float*)d_in[13];
  const float* bp1 = (const float*)d_in[14];
  const float* g1 = (const float*)d_in[15];
  const float* b1 = (const float*)d_in[16];

  char* ws = (char*)d_ws;
  const size_t MB = 1u << 20;
  u16* Abf = (u16*)(ws);               // 16 MB; reused as attn-x buffer
  u16* Wtqkv = (u16*)(ws + 16 * MB);   // 6 MB
  u16* Wtp2 = (u16*)(ws + 22 * MB);    // 2 MB
  u16* qbuf = (u16*)(ws + 24 * MB);    // 16 MB
  u16* kbuf = (u16*)(ws + 40 * MB);    // 16 MB  fragment-major
  u16* vbuf = (u16*)(ws + 56 * MB);    // 16 MB  fragment-major
  u16* ybuf = (u16*)(ws + 72 * MB);    // 16 MB bf16 y
  float* vhat = (float*)(ws + 88 * MB);            // 32 KB
  float* sim_g = (float*)(ws + 88 * MB + 65536);   // 32 KB
  float* ttpre = (float*)(ws + 88 * MB + 131072);  // 32 KB
  float* ttv = (float*)(ws + 88 * MB + 196608);    // 32 KB

  float* out = (float*)d_out;
  float* tt_out = out;             // 8*1024
  float* tf_out = out + 8 * 1024;  // 8*1024*1024

  prep_kernel<<<dim3(12297), dim3(256), 0, stream>>>(text, Abf, Wqkv, Wtqkv, Wp2, Wtp2, vis,
                                                     vhat, ttpre);
  gemm_bt<<<dim3(24, 64), dim3(256), 0, stream>>>(Abf, Wtqkv, bqkv, 8192, 3072, 1024, 0, qbuf,
                                                  kbuf, vbuf, (u16*)nullptr);
  attn_kernel<<<dim3(8192), dim3(512), 40640, stream>>>(qbuf, kbuf, vbuf, mask, Abf);
  gemm_bt<<<dim3(8, 64), dim3(256), 0, stream>>>(Abf, Wtp2, bp2, 8192, 1024, 1024, 1,
                                                 (u16*)nullptr, (u16*)nullptr, (u16*)nullptr,
                                                 ybuf);
  resid_ln<<<dim3(1024), dim3(512), 0, stream>>>(ybuf, text, g2, b2, vhat, mask, alpha, beta,
                                                 tf_out, sim_g);
  topk_pool<<<dim3(8, 4), dim3(256), 0, stream>>>(sim_g, tf_out, ttpre);
  matvec_p1<<<dim3(8, 16), dim3(256), 0, stream>>>(ttpre, txt, Wp1, bp1, ttv);
  ln_tt<<<dim3(8), dim3(256), 0, stream>>>(ttv, g1, b1, tt_out);
}